// Round 2
// baseline (1033.939 us; speedup 1.0000x reference)
//
#include <hip/hip_runtime.h>
#include <hip/hip_bf16.h>
#include <math.h>

// ---------------------------------------------------------------------------
// BasicTransformer block on MI355X, bf16-MFMA implementation.
// B=2 S=2048 H=2048 NH=32 HD=64 FFN=8192
// ---------------------------------------------------------------------------

typedef __attribute__((ext_vector_type(8))) short bf16x8;
typedef __attribute__((ext_vector_type(4))) float f32x4;
typedef __attribute__((ext_vector_type(16))) float f32x16;

#define DEV __device__ __forceinline__

static constexpr int SEQ  = 2048;
static constexpr int HID  = 2048;
static constexpr int NHEAD = 32;
static constexpr int HDIM = 64;
static constexpr int NFFN = 8192;
static constexpr int NTOK = 2 * SEQ;       // 4096 rows
static constexpr int QKVW = 3 * HID;       // 6144

// 0.125 (1/sqrt(64)) * log2(e): folded into Q so P = exp2(S - m)
#define QSCALE 0.1803368801111204f

#if defined(__has_builtin)
#if __has_builtin(__builtin_amdgcn_exp2f)
#define EXP2(x) __builtin_amdgcn_exp2f(x)
#endif
#endif
#ifndef EXP2
#define EXP2(x) exp2f(x)
#endif

DEV ushort f2bf(float f) {                 // RNE f32 -> bf16
  unsigned u = __float_as_uint(f);
  return (ushort)((u + 0x7fffu + ((u >> 16) & 1u)) >> 16);
}

DEV void gload16(const void* g, void* l) { // async global->LDS, 16B/lane
  __builtin_amdgcn_global_load_lds(
      (const __attribute__((address_space(1))) unsigned int*)g,
      (__attribute__((address_space(3))) unsigned int*)l, 16, 0, 0);
}

// ---------------------------------------------------------------------------
// transpose + convert: in [R][C] f32  ->  out [C][R] bf16
// ---------------------------------------------------------------------------
__global__ __launch_bounds__(256) void tcvt_kernel(const float* __restrict__ in,
                                                   ushort* __restrict__ out,
                                                   int R, int C) {
  __shared__ ushort tile[64][72];          // +8 pad breaks bank conflicts
  const int tr = blockIdx.y * 64, tc = blockIdx.x * 64;
  const int t = threadIdx.x;
  const int rr = t >> 2, c4 = (t & 3) * 16;
  const float4* ip = (const float4*)(in + (size_t)(tr + rr) * C + tc + c4);
  float4 a0 = ip[0], a1 = ip[1], a2 = ip[2], a3 = ip[3];
  ushort* tp = &tile[rr][c4];
  tp[0]=f2bf(a0.x); tp[1]=f2bf(a0.y); tp[2]=f2bf(a0.z); tp[3]=f2bf(a0.w);
  tp[4]=f2bf(a1.x); tp[5]=f2bf(a1.y); tp[6]=f2bf(a1.z); tp[7]=f2bf(a1.w);
  tp[8]=f2bf(a2.x); tp[9]=f2bf(a2.y); tp[10]=f2bf(a2.z); tp[11]=f2bf(a2.w);
  tp[12]=f2bf(a3.x); tp[13]=f2bf(a3.y); tp[14]=f2bf(a3.z); tp[15]=f2bf(a3.w);
  __syncthreads();
  union { ushort u[8]; bf16x8 v; } p0, p1;
#pragma unroll
  for (int j = 0; j < 8; ++j) { p0.u[j] = tile[c4 + j][rr]; p1.u[j] = tile[c4 + 8 + j][rr]; }
  ushort* op = out + (size_t)(tc + rr) * R + tr + c4;
  *(bf16x8*)op = p0.v;
  *(bf16x8*)(op + 8) = p1.v;
}

// ---------------------------------------------------------------------------
// V transpose (bf16->bf16): per (b,h) gather V [2048 s][64 d] -> VT [64 d][2048 s]
// ---------------------------------------------------------------------------
__global__ __launch_bounds__(256) void vtrans_kernel(const ushort* __restrict__ qkv,
                                                     ushort* __restrict__ vt) {
  __shared__ ushort tile[64][72];
  const int s0 = blockIdx.x * 64, bh = blockIdx.y;
  const int b = bh >> 5, h = bh & 31;
  const int t = threadIdx.x;
  const int r = t >> 2, c0 = (t & 3) * 16;
  const ushort* ip = qkv + ((size_t)(b * SEQ + s0 + r)) * QKVW + h * 192 + 128 + c0;
  *(bf16x8*)&tile[r][c0]     = *(const bf16x8*)ip;
  *(bf16x8*)&tile[r][c0 + 8] = *(const bf16x8*)(ip + 8);
  __syncthreads();
  union { ushort u[8]; bf16x8 v; } p0, p1;
#pragma unroll
  for (int j = 0; j < 8; ++j) { p0.u[j] = tile[c0 + j][r]; p1.u[j] = tile[c0 + 8 + j][r]; }
  ushort* op = vt + ((size_t)(bh * 64 + r)) * SEQ + s0 + c0;
  *(bf16x8*)op = p0.v;
  *(bf16x8*)(op + 8) = p1.v;
}

// ---------------------------------------------------------------------------
// LayerNorm row kernel: x [rows][2048] f32 -> out bf16
// ---------------------------------------------------------------------------
__global__ __launch_bounds__(256) void ln_kernel(const float* __restrict__ x,
                                                 const float* __restrict__ g,
                                                 const float* __restrict__ bb,
                                                 ushort* __restrict__ out) {
  const int row = blockIdx.x, t = threadIdx.x;
  const float4* xv = (const float4*)(x + (size_t)row * HID);
  float4 a0 = xv[t * 2], a1 = xv[t * 2 + 1];
  float s  = a0.x + a0.y + a0.z + a0.w + a1.x + a1.y + a1.z + a1.w;
  float ss = a0.x*a0.x + a0.y*a0.y + a0.z*a0.z + a0.w*a0.w
           + a1.x*a1.x + a1.y*a1.y + a1.z*a1.z + a1.w*a1.w;
#pragma unroll
  for (int o = 32; o > 0; o >>= 1) { s += __shfl_down(s, o); ss += __shfl_down(ss, o); }
  __shared__ float red[8];
  const int w = t >> 6, l = t & 63;
  if (l == 0) { red[w] = s; red[4 + w] = ss; }
  __syncthreads();
  s  = red[0] + red[1] + red[2] + red[3];
  ss = red[4] + red[5] + red[6] + red[7];
  const float mu = s * (1.f / HID);
  const float rs = rsqrtf(ss * (1.f / HID) - mu * mu + 1e-5f);
  const float4* gv = (const float4*)g;
  const float4* bv = (const float4*)bb;
  float4 g0 = gv[t * 2], g1 = gv[t * 2 + 1], b0 = bv[t * 2], b1 = bv[t * 2 + 1];
  union { ushort u[8]; bf16x8 v; } p;
  p.u[0] = f2bf((a0.x - mu) * rs * g0.x + b0.x);
  p.u[1] = f2bf((a0.y - mu) * rs * g0.y + b0.y);
  p.u[2] = f2bf((a0.z - mu) * rs * g0.z + b0.z);
  p.u[3] = f2bf((a0.w - mu) * rs * g0.w + b0.w);
  p.u[4] = f2bf((a1.x - mu) * rs * g1.x + b1.x);
  p.u[5] = f2bf((a1.y - mu) * rs * g1.y + b1.y);
  p.u[6] = f2bf((a1.z - mu) * rs * g1.z + b1.z);
  p.u[7] = f2bf((a1.w - mu) * rs * g1.w + b1.w);
  *(bf16x8*)(out + (size_t)row * HID + t * 8) = p.v;
}

// ---------------------------------------------------------------------------
// GEMM: C[M,N] = A[M,K](bf16) * BT[N,K](bf16)^T, fused epilogues.
// EPI 0: +bias -> bf16 out (Q-cols pre-scaled by QSCALE)
// EPI 1: +bias +res -> f32 out     EPI 2: +bias, gelu -> bf16
// ---------------------------------------------------------------------------
template <int EPI>
__global__ __launch_bounds__(256) void gemm_kernel(const ushort* __restrict__ A,
                                                   const ushort* __restrict__ BT,
                                                   const float* __restrict__ bias,
                                                   const float* __restrict__ res,
                                                   void* __restrict__ outv,
                                                   int M, int N, int K) {
  __shared__ ushort As[128 * 64];
  __shared__ ushort Bs[128 * 64];
  const int t = threadIdx.x, w = t >> 6, l = t & 63;
  const int bn = blockIdx.x, bm = blockIdx.y;
  const int wr = w >> 1, wc = w & 1;
  const int l16 = l & 15, lg = l >> 4;
  const f32x4 z4 = {0.f, 0.f, 0.f, 0.f};
  f32x4 acc[4][4];
#pragma unroll
  for (int i = 0; i < 4; ++i)
#pragma unroll
    for (int j = 0; j < 4; ++j) acc[i][j] = z4;

  const ushort* aG = A  + ((size_t)bm * 128 + w * 32 + (l >> 3)) * K + (l & 7) * 8;
  const ushort* bG = BT + ((size_t)bn * 128 + w * 32 + (l >> 3)) * K + (l & 7) * 8;
  ushort* aS = &As[w * 32 * 64 + l * 8];
  ushort* bS = &Bs[w * 32 * 64 + l * 8];

  for (int kt = 0; kt < K; kt += 64) {
#pragma unroll
    for (int i = 0; i < 4; ++i) {
      gload16(aG + (size_t)i * 8 * K + kt, aS + i * 8 * 64);
      gload16(bG + (size_t)i * 8 * K + kt, bS + i * 8 * 64);
    }
    __syncthreads();
#pragma unroll
    for (int kk = 0; kk < 2; ++kk) {
      const int ko = kk * 32 + lg * 8;
      bf16x8 af[4], bfv[4];
#pragma unroll
      for (int mi = 0; mi < 4; ++mi)
        af[mi] = *(const bf16x8*)&As[(wr * 64 + mi * 16 + l16) * 64 + ko];
#pragma unroll
      for (int ni = 0; ni < 4; ++ni)
        bfv[ni] = *(const bf16x8*)&Bs[(wc * 64 + ni * 16 + l16) * 64 + ko];
#pragma unroll
      for (int mi = 0; mi < 4; ++mi)
#pragma unroll
        for (int ni = 0; ni < 4; ++ni)
          acc[mi][ni] = __builtin_amdgcn_mfma_f32_16x16x32_bf16(af[mi], bfv[ni], acc[mi][ni], 0, 0, 0);
    }
    __syncthreads();
  }

  const int col0 = bn * 128 + wc * 64 + l16;
  const int row0 = bm * 128 + wr * 64 + lg * 4;
#pragma unroll
  for (int ni = 0; ni < 4; ++ni) {
    const int col = col0 + ni * 16;
    const float bvl = bias[col];
    const bool qcol = (EPI == 0) && ((col % 192) < 64);
#pragma unroll
    for (int mi = 0; mi < 4; ++mi) {
#pragma unroll
      for (int r = 0; r < 4; ++r) {
        const int row = row0 + mi * 16 + r;
        const size_t off = (size_t)row * N + col;
        float v = acc[mi][ni][r] + bvl;
        if (EPI == 1) {
          ((float*)outv)[off] = v + res[off];
        } else if (EPI == 2) {
          const float u = 0.7978845608f * (v + 0.044715f * v * v * v);
          ((ushort*)outv)[off] = f2bf(v / (1.f + __expf(-2.f * u)));
        } else {
          if (qcol) v *= QSCALE;
          ((ushort*)outv)[off] = f2bf(v);
        }
      }
    }
  }
}

// ---------------------------------------------------------------------------
// Flash attention v2: zero-LDS, 32x32x16 MFMA, swapped QK^T, in-register
// softmax (cvt_pk + permlane32_swap), defer-max, XCD-pinned block swizzle.
// Grid (16, 64): 4 indep waves/block, each wave = 32 q rows. KV tile = 32.
// ---------------------------------------------------------------------------
__global__ __launch_bounds__(256) void attn_kernel(const ushort* __restrict__ qkv,
                                                   const ushort* __restrict__ vt,
                                                   ushort* __restrict__ ctx) {
  // XCD-bijective swizzle: 1024 blocks = 8 XCD x 128; each XCD owns 8 heads.
  const int lin = blockIdx.x + blockIdx.y * gridDim.x;
  const int work = (lin & 7) * 128 + (lin >> 3);
  const int qt = work & 15, bh = work >> 4;
  const int b = bh >> 5, h = bh & 31;
  const int t = threadIdx.x, w = t >> 6, l = t & 63;
  const int l32 = l & 31, hi = l >> 5;

  // Q fragments: lane holds Q[q=l32][s*16 + hi*8 + j], s=0..3 (pre-scaled)
  const ushort* qp = qkv + ((size_t)(b * SEQ + qt * 128 + w * 32 + l32)) * QKVW
                   + h * 192 + hi * 8;
  bf16x8 qf0 = *(const bf16x8*)(qp);
  bf16x8 qf1 = *(const bf16x8*)(qp + 16);
  bf16x8 qf2 = *(const bf16x8*)(qp + 32);
  bf16x8 qf3 = *(const bf16x8*)(qp + 48);

  const ushort* kptr = qkv + ((size_t)b * SEQ) * QKVW + h * 192 + 64
                     + (size_t)l32 * QKVW + hi * 8;
  const ushort* vpl = vt + ((size_t)(bh * 64 + l32)) * SEQ + hi * 8;

  f32x16 oacc0, oacc1;
#pragma unroll
  for (int r = 0; r < 16; ++r) { oacc0[r] = 0.f; oacc1[r] = 0.f; }
  float m = -1e30f, lsum = 0.f;
  const f32x16 z16 = {};

  for (int kv0 = 0; kv0 < SEQ; kv0 += 32) {
    // --- K fragments (A-operand), 4 hd slices ---
    bf16x8 kf0 = *(const bf16x8*)(kptr);
    bf16x8 kf1 = *(const bf16x8*)(kptr + 16);
    bf16x8 kf2 = *(const bf16x8*)(kptr + 32);
    bf16x8 kf3 = *(const bf16x8*)(kptr + 48);
    kptr += 32 * QKVW;
    // --- V^T fragments (B-operand): [kslice][dtile] ---
    bf16x8 vf00 = *(const bf16x8*)(vpl + kv0);
    bf16x8 vf01 = *(const bf16x8*)(vpl + kv0 + 32 * SEQ);
    bf16x8 vf10 = *(const bf16x8*)(vpl + kv0 + 16);
    bf16x8 vf11 = *(const bf16x8*)(vpl + kv0 + 16 + 32 * SEQ);
    // --- S^T[kv][q] = K . Q^T  (lane = q col, kv in regs) ---
    f32x16 s = __builtin_amdgcn_mfma_f32_32x32x16_bf16(kf0, qf0, z16, 0, 0, 0);
    s = __builtin_amdgcn_mfma_f32_32x32x16_bf16(kf1, qf1, s, 0, 0, 0);
    s = __builtin_amdgcn_mfma_f32_32x32x16_bf16(kf2, qf2, s, 0, 0, 0);
    s = __builtin_amdgcn_mfma_f32_32x32x16_bf16(kf3, qf3, s, 0, 0, 0);
    // --- row max (this lane's 16 kv + partner lane's 16) ---
    float tm = s[0];
#pragma unroll
    for (int r = 1; r < 16; ++r) tm = fmaxf(tm, s[r]);
    tm = fmaxf(tm, __shfl_xor(tm, 32));
    // --- defer-max: rescale only when max grew by >8 (log2 domain) ---
    if (!__all(tm - m <= 8.f)) {
      const float mn = fmaxf(m, tm);
      const float sf = EXP2(m - mn);
      m = mn;
      lsum *= sf;
#pragma unroll
      for (int r = 0; r < 16; ++r) {
        const float f = __shfl(sf, (r & 3) + 8 * (r >> 2) + 4 * hi);
        oacc0[r] *= f; oacc1[r] *= f;
      }
    }
    // --- P = exp2(S - m), accumulate row-sum ---
    float p[16];
#pragma unroll
    for (int r = 0; r < 16; ++r) p[r] = EXP2(s[r] - m);
    float ls = 0.f;
#pragma unroll
    for (int r = 0; r < 16; ++r) ls += p[r];
    lsum += ls;
    // --- pack to bf16 pairs, permlane-swap into PV A-fragment layout ---
    unsigned pw[8];
#pragma unroll
    for (int i = 0; i < 8; ++i)
      asm("v_cvt_pk_bf16_f32 %0, %1, %2" : "=v"(pw[i]) : "v"(p[2 * i]), "v"(p[2 * i + 1]));
    unsigned a0 = pw[0], b0 = pw[2];
    asm("v_permlane32_swap_b32 %0, %1" : "+v"(a0), "+v"(b0));
    unsigned a1 = pw[1], b1 = pw[3];
    asm("v_permlane32_swap_b32 %0, %1" : "+v"(a1), "+v"(b1));
    unsigned a2 = pw[4], b2 = pw[6];
    asm("v_permlane32_swap_b32 %0, %1" : "+v"(a2), "+v"(b2));
    unsigned a3 = pw[5], b3 = pw[7];
    asm("v_permlane32_swap_b32 %0, %1" : "+v"(a3), "+v"(b3));
    union { unsigned w[4]; bf16x8 v; } pa0, pa1;
    pa0.w[0] = a0; pa0.w[1] = a1; pa0.w[2] = b0; pa0.w[3] = b1;
    pa1.w[0] = a2; pa1.w[1] = a3; pa1.w[2] = b2; pa1.w[3] = b3;
    // --- O[q][d] += P . V ---
    oacc0 = __builtin_amdgcn_mfma_f32_32x32x16_bf16(pa0.v, vf00, oacc0, 0, 0, 0);
    oacc1 = __builtin_amdgcn_mfma_f32_32x32x16_bf16(pa0.v, vf01, oacc1, 0, 0, 0);
    oacc0 = __builtin_amdgcn_mfma_f32_32x32x16_bf16(pa1.v, vf10, oacc0, 0, 0, 0);
    oacc1 = __builtin_amdgcn_mfma_f32_32x32x16_bf16(pa1.v, vf11, oacc1, 0, 0, 0);
  }

  // --- normalize (l lives lane=q; O has q in regs -> bpermute) + store ---
  const float lf = lsum + __shfl_xor(lsum, 32);
  const float linv = 1.f / lf;
#pragma unroll
  for (int r = 0; r < 16; ++r) {
    const int qr = (r & 3) + 8 * (r >> 2);
    const float fac = __shfl(linv, qr + 4 * hi);
    const int row = qt * 128 + w * 32 + qr + 4 * hi;
    const size_t base = ((size_t)(b * SEQ + row)) * HID + h * 64 + l32;
    ctx[base]      = f2bf(oacc0[r] * fac);
    ctx[base + 32] = f2bf(oacc1[r] * fac);
  }
}

// ---------------------------------------------------------------------------
extern "C" void kernel_launch(void* const* d_in, const int* in_sizes, int n_in,
                              void* d_out, int out_size, void* d_ws, size_t ws_size,
                              hipStream_t stream) {
  const float* x      = (const float*)d_in[0];
  const float* ln1g   = (const float*)d_in[1];
  const float* ln1b   = (const float*)d_in[2];
  const float* w_qkv  = (const float*)d_in[3];
  const float* b_qkv  = (const float*)d_in[4];
  const float* w_proj = (const float*)d_in[5];
  const float* b_proj = (const float*)d_in[6];
  const float* ln2g   = (const float*)d_in[7];
  const float* ln2b   = (const float*)d_in[8];
  const float* w1     = (const float*)d_in[9];
  const float* b1     = (const float*)d_in[10];
  const float* w2     = (const float*)d_in[11];
  const float* b2     = (const float*)d_in[12];

  char* ws = (char*)d_ws;
  ushort* wqkvT = (ushort*)(ws + 0);            // [6144][2048] bf16  25165824
  ushort* wprojT = (ushort*)(ws + 25165824);    // [2048][2048] bf16   8388608
  ushort* w1T   = (ushort*)(ws + 33554432);     // [8192][2048] bf16  33554432
  ushort* w2T   = (ushort*)(ws + 67108864);     // [2048][8192] bf16  33554432
  ushort* hbuf  = (ushort*)(ws + 100663296);    // 16MB: LN out, then V^T, then LN2 out
  ushort* qkvb  = (ushort*)(ws + 117440512);    // [4096][6144] bf16 (reused as gelu) 67108864
  ushort* ctxb  = (ushort*)(ws + 184549376);    // [4096][2048] bf16  16777216
  float*  x2    = (float*)(ws + 201326592);     // [4096][2048] f32   33554432

  tcvt_kernel<<<dim3(96, 32),  256, 0, stream>>>(w_qkv,  wqkvT, 2048, 6144);
  tcvt_kernel<<<dim3(32, 32),  256, 0, stream>>>(w_proj, wprojT, 2048, 2048);
  tcvt_kernel<<<dim3(128, 32), 256, 0, stream>>>(w1,     w1T,   2048, 8192);
  tcvt_kernel<<<dim3(32, 128), 256, 0, stream>>>(w2,     w2T,   8192, 2048);

  // LN1 -> hbuf (bf16)
  ln_kernel<<<NTOK, 256, 0, stream>>>(x, ln1g, ln1b, hbuf);
  // QKV = h @ w_qkv + b_qkv (Q cols pre-scaled by 0.125*log2e)
  gemm_kernel<0><<<dim3(48, 32), 256, 0, stream>>>(hbuf, wqkvT, b_qkv, nullptr, qkvb, NTOK, QKVW, HID);
  // V^T into hbuf (LN1 output now dead)
  vtrans_kernel<<<dim3(SEQ / 64, 2 * NHEAD), 256, 0, stream>>>(qkvb, hbuf);
  // attention -> ctxb (bf16)
  attn_kernel<<<dim3(16, 2 * NHEAD), 256, 0, stream>>>(qkvb, hbuf, ctxb);
  // x2 = ctx @ w_proj + b_proj + x   (f32)
  gemm_kernel<1><<<dim3(16, 32), 256, 0, stream>>>(ctxb, wprojT, b_proj, x, x2, NTOK, HID, HID);
  // LN2 -> hbuf
  ln_kernel<<<NTOK, 256, 0, stream>>>(x2, ln2g, ln2b, hbuf);
  // g = gelu(h @ w1 + b1)
  gemm_kernel<2><<<dim3(64, 32), 256, 0, stream>>>(hbuf, w1T, b1, nullptr, qkvb, NTOK, NFFN, HID);
  // out = g @ w2 + b2 + x2
  gemm_kernel<1><<<dim3(16, 32), 256, 0, stream>>>(qkvb, w2T, b2, x2, (float*)d_out, NTOK, HID, NFFN);
}

// Round 3
// 848.374 us; speedup vs baseline: 1.2187x; 1.2187x over previous
//
#include <hip/hip_runtime.h>
#include <hip/hip_bf16.h>
#include <math.h>

// ---------------------------------------------------------------------------
// BasicTransformer block on MI355X, bf16-MFMA implementation.
// B=2 S=2048 H=2048 NH=32 HD=64 FFN=8192
// Attn v3: QKV GEMM writes Q/K/V in MFMA-fragment-packed order; attention
// reads fully-coalesced 16B/lane from global (L2-resident), zero LDS.
// ---------------------------------------------------------------------------

typedef __attribute__((ext_vector_type(8))) short bf16x8;
typedef __attribute__((ext_vector_type(4))) float f32x4;
typedef __attribute__((ext_vector_type(16))) float f32x16;

#define DEV __device__ __forceinline__

static constexpr int SEQ  = 2048;
static constexpr int HID  = 2048;
static constexpr int NHEAD = 32;
static constexpr int HDIM = 64;
static constexpr int NFFN = 8192;
static constexpr int NTOK = 2 * SEQ;       // 4096 rows
static constexpr int QKVW = 3 * HID;       // 6144

// 0.125 (1/sqrt(64)) * log2(e): folded into Q so P = exp2(S - m)
#define QSCALE 0.1803368801111204f

#if defined(__has_builtin)
#if __has_builtin(__builtin_amdgcn_exp2f)
#define EXP2(x) __builtin_amdgcn_exp2f(x)
#endif
#endif
#ifndef EXP2
#define EXP2(x) exp2f(x)
#endif

DEV ushort f2bf(float f) {                 // RNE f32 -> bf16
  unsigned u = __float_as_uint(f);
  return (ushort)((u + 0x7fffu + ((u >> 16) & 1u)) >> 16);
}

DEV void gload16(const void* g, void* l) { // async global->LDS, 16B/lane
  __builtin_amdgcn_global_load_lds(
      (const __attribute__((address_space(1))) unsigned int*)g,
      (__attribute__((address_space(3))) unsigned int*)l, 16, 0, 0);
}

// ---------------------------------------------------------------------------
// transpose + convert: in [R][C] f32  ->  out [C][R] bf16
// ---------------------------------------------------------------------------
__global__ __launch_bounds__(256) void tcvt_kernel(const float* __restrict__ in,
                                                   ushort* __restrict__ out,
                                                   int R, int C) {
  __shared__ ushort tile[64][72];          // +8 pad breaks bank conflicts
  const int tr = blockIdx.y * 64, tc = blockIdx.x * 64;
  const int t = threadIdx.x;
  const int rr = t >> 2, c4 = (t & 3) * 16;
  const float4* ip = (const float4*)(in + (size_t)(tr + rr) * C + tc + c4);
  float4 a0 = ip[0], a1 = ip[1], a2 = ip[2], a3 = ip[3];
  ushort* tp = &tile[rr][c4];
  tp[0]=f2bf(a0.x); tp[1]=f2bf(a0.y); tp[2]=f2bf(a0.z); tp[3]=f2bf(a0.w);
  tp[4]=f2bf(a1.x); tp[5]=f2bf(a1.y); tp[6]=f2bf(a1.z); tp[7]=f2bf(a1.w);
  tp[8]=f2bf(a2.x); tp[9]=f2bf(a2.y); tp[10]=f2bf(a2.z); tp[11]=f2bf(a2.w);
  tp[12]=f2bf(a3.x); tp[13]=f2bf(a3.y); tp[14]=f2bf(a3.z); tp[15]=f2bf(a3.w);
  __syncthreads();
  union { ushort u[8]; bf16x8 v; } p0, p1;
#pragma unroll
  for (int j = 0; j < 8; ++j) { p0.u[j] = tile[c4 + j][rr]; p1.u[j] = tile[c4 + 8 + j][rr]; }
  ushort* op = out + (size_t)(tc + rr) * R + tr + c4;
  *(bf16x8*)op = p0.v;
  *(bf16x8*)(op + 8) = p1.v;
}

// ---------------------------------------------------------------------------
// LayerNorm row kernel: x [rows][2048] f32 -> out bf16
// ---------------------------------------------------------------------------
__global__ __launch_bounds__(256) void ln_kernel(const float* __restrict__ x,
                                                 const float* __restrict__ g,
                                                 const float* __restrict__ bb,
                                                 ushort* __restrict__ out) {
  const int row = blockIdx.x, t = threadIdx.x;
  const float4* xv = (const float4*)(x + (size_t)row * HID);
  float4 a0 = xv[t * 2], a1 = xv[t * 2 + 1];
  float s  = a0.x + a0.y + a0.z + a0.w + a1.x + a1.y + a1.z + a1.w;
  float ss = a0.x*a0.x + a0.y*a0.y + a0.z*a0.z + a0.w*a0.w
           + a1.x*a1.x + a1.y*a1.y + a1.z*a1.z + a1.w*a1.w;
#pragma unroll
  for (int o = 32; o > 0; o >>= 1) { s += __shfl_down(s, o); ss += __shfl_down(ss, o); }
  __shared__ float red[8];
  const int w = t >> 6, l = t & 63;
  if (l == 0) { red[w] = s; red[4 + w] = ss; }
  __syncthreads();
  s  = red[0] + red[1] + red[2] + red[3];
  ss = red[4] + red[5] + red[6] + red[7];
  const float mu = s * (1.f / HID);
  const float rs = rsqrtf(ss * (1.f / HID) - mu * mu + 1e-5f);
  const float4* gv = (const float4*)g;
  const float4* bv = (const float4*)bb;
  float4 g0 = gv[t * 2], g1 = gv[t * 2 + 1], b0 = bv[t * 2], b1 = bv[t * 2 + 1];
  union { ushort u[8]; bf16x8 v; } p;
  p.u[0] = f2bf((a0.x - mu) * rs * g0.x + b0.x);
  p.u[1] = f2bf((a0.y - mu) * rs * g0.y + b0.y);
  p.u[2] = f2bf((a0.z - mu) * rs * g0.z + b0.z);
  p.u[3] = f2bf((a0.w - mu) * rs * g0.w + b0.w);
  p.u[4] = f2bf((a1.x - mu) * rs * g1.x + b1.x);
  p.u[5] = f2bf((a1.y - mu) * rs * g1.y + b1.y);
  p.u[6] = f2bf((a1.z - mu) * rs * g1.z + b1.z);
  p.u[7] = f2bf((a1.w - mu) * rs * g1.w + b1.w);
  *(bf16x8*)(out + (size_t)row * HID + t * 8) = p.v;
}

// ---------------------------------------------------------------------------
// GEMM core macro body shared by the generic and QKV-packing variants.
// C[M,N] = A[M,K](bf16) * BT[N,K](bf16)^T. 128x128 tile, BK=64, 4 waves.
// ---------------------------------------------------------------------------
#define GEMM_MAIN_LOOP()                                                      \
  __shared__ ushort As[128 * 64];                                             \
  __shared__ ushort Bs[128 * 64];                                             \
  const int t = threadIdx.x, w = t >> 6, l = t & 63;                          \
  const int bn = blockIdx.x, bm = blockIdx.y;                                 \
  const int wr = w >> 1, wc = w & 1;                                          \
  const int l16 = l & 15, lg = l >> 4;                                        \
  const f32x4 z4 = {0.f, 0.f, 0.f, 0.f};                                      \
  f32x4 acc[4][4];                                                            \
  _Pragma("unroll") for (int i = 0; i < 4; ++i)                               \
    _Pragma("unroll") for (int j = 0; j < 4; ++j) acc[i][j] = z4;             \
  const ushort* aG = A  + ((size_t)bm * 128 + w * 32 + (l >> 3)) * K + (l & 7) * 8; \
  const ushort* bG = BT + ((size_t)bn * 128 + w * 32 + (l >> 3)) * K + (l & 7) * 8; \
  ushort* aS = &As[w * 32 * 64 + l * 8];                                      \
  ushort* bS = &Bs[w * 32 * 64 + l * 8];                                      \
  for (int kt = 0; kt < K; kt += 64) {                                        \
    _Pragma("unroll") for (int i = 0; i < 4; ++i) {                           \
      gload16(aG + (size_t)i * 8 * K + kt, aS + i * 8 * 64);                  \
      gload16(bG + (size_t)i * 8 * K + kt, bS + i * 8 * 64);                  \
    }                                                                         \
    __syncthreads();                                                          \
    _Pragma("unroll") for (int kk = 0; kk < 2; ++kk) {                        \
      const int ko = kk * 32 + lg * 8;                                        \
      bf16x8 af[4], bfv[4];                                                   \
      _Pragma("unroll") for (int mi = 0; mi < 4; ++mi)                        \
        af[mi] = *(const bf16x8*)&As[(wr * 64 + mi * 16 + l16) * 64 + ko];    \
      _Pragma("unroll") for (int ni = 0; ni < 4; ++ni)                        \
        bfv[ni] = *(const bf16x8*)&Bs[(wc * 64 + ni * 16 + l16) * 64 + ko];   \
      _Pragma("unroll") for (int mi = 0; mi < 4; ++mi)                        \
        _Pragma("unroll") for (int ni = 0; ni < 4; ++ni)                      \
          acc[mi][ni] = __builtin_amdgcn_mfma_f32_16x16x32_bf16(af[mi], bfv[ni], acc[mi][ni], 0, 0, 0); \
    }                                                                         \
    __syncthreads();                                                          \
  }                                                                           \
  const int col0 = bn * 128 + wc * 64 + l16;                                  \
  const int row0 = bm * 128 + wr * 64 + lg * 4;

// Generic epilogues: EPI 1: +bias +res -> f32   EPI 2: +bias, gelu -> bf16
template <int EPI>
__global__ __launch_bounds__(256) void gemm_kernel(const ushort* __restrict__ A,
                                                   const ushort* __restrict__ BT,
                                                   const float* __restrict__ bias,
                                                   const float* __restrict__ res,
                                                   void* __restrict__ outv,
                                                   int M, int N, int K) {
  GEMM_MAIN_LOOP()
#pragma unroll
  for (int ni = 0; ni < 4; ++ni) {
    const int col = col0 + ni * 16;
    const float bvl = bias[col];
#pragma unroll
    for (int mi = 0; mi < 4; ++mi) {
#pragma unroll
      for (int r = 0; r < 4; ++r) {
        const int row = row0 + mi * 16 + r;
        const size_t off = (size_t)row * N + col;
        float v = acc[mi][ni][r] + bvl;
        if (EPI == 1) {
          ((float*)outv)[off] = v + res[off];
        } else if (EPI == 2) {
          const float u = 0.7978845608f * (v + 0.044715f * v * v * v);
          ((ushort*)outv)[off] = f2bf(v / (1.f + __expf(-2.f * u)));
        } else {
          ((ushort*)outv)[off] = f2bf(v);
        }
      }
    }
  }
}

// QKV GEMM: writes Q/K/V directly in MFMA-fragment-packed order.
// Q,K: [bh][tile32][s-slice 0..3][lane 0..63][j 0..7], lane=(d>>3&1)*32+row5
// V:   [bh][tile32][ks 0..1][half 0..1][lane 0..63][j], lane=(kv>>3&1)*32+(d&31)
__global__ __launch_bounds__(256) void gemm_qkv_kernel(const ushort* __restrict__ A,
                                                       const ushort* __restrict__ BT,
                                                       const float* __restrict__ bias,
                                                       ushort* __restrict__ qpk,
                                                       ushort* __restrict__ kpk,
                                                       ushort* __restrict__ vpk,
                                                       int M, int N, int K) {
  GEMM_MAIN_LOOP()
#pragma unroll
  for (int ni = 0; ni < 4; ++ni) {
    const int col = col0 + ni * 16;
    const float bvl = bias[col];
    const int h = col / 192;
    const int c = col - h * 192;        // 0..191: Q / K / V section
#pragma unroll
    for (int mi = 0; mi < 4; ++mi) {
#pragma unroll
      for (int r = 0; r < 4; ++r) {
        const int row = row0 + mi * 16 + r;
        float v = acc[mi][ni][r] + bvl;
        const int bh2 = (row >> 11) * 32 + h;
        const int t32 = (row >> 5) & 63;
        const int r5 = row & 31;
        if (c < 64) {
          v *= QSCALE;
          const int s = c >> 4, hi2 = (c >> 3) & 1, j = c & 7;
          qpk[(((size_t)bh2 * 64 + t32) * 4 + s) * 512 + (hi2 * 32 + r5) * 8 + j] = f2bf(v);
        } else if (c < 128) {
          const int d = c - 64;
          const int s = d >> 4, hi2 = (d >> 3) & 1, j = d & 7;
          kpk[(((size_t)bh2 * 64 + t32) * 4 + s) * 512 + (hi2 * 32 + r5) * 8 + j] = f2bf(v);
        } else {
          const int d = c - 128;
          const int ks = r5 >> 4, hi2 = (r5 >> 3) & 1, j = r5 & 7;
          const int half = d >> 5, dl = d & 31;
          vpk[((((size_t)bh2 * 64 + t32) * 2 + ks) * 2 + half) * 512 + (hi2 * 32 + dl) * 8 + j] = f2bf(v);
        }
      }
    }
  }
}

// ---------------------------------------------------------------------------
// Flash attention v3: zero-LDS, all operands fragment-packed & coalesced.
// Grid (16,64). 4 indep waves/block, wave = 32 q rows, KV tile = 32.
// K reg-prefetched 1 tile ahead; V issued at step top (consumed post-softmax).
// ---------------------------------------------------------------------------
__global__ __launch_bounds__(256) void attn_kernel(const ushort* __restrict__ qpk,
                                                   const ushort* __restrict__ kpk,
                                                   const ushort* __restrict__ vpk,
                                                   ushort* __restrict__ ctx) {
  // XCD-bijective swizzle: 1024 blocks = 8 XCD x 128; each XCD owns 8 heads.
  const int lin = blockIdx.x + blockIdx.y * gridDim.x;
  const int work = (lin & 7) * 128 + (lin >> 3);
  const int qt = work & 15, bh = work >> 4;
  const int b = bh >> 5, h = bh & 31;
  const int t = threadIdx.x, w = t >> 6, l = t & 63;
  const int l32 = l & 31, hi = l >> 5;

  const ushort* qb = qpk + ((((size_t)bh * 64 + qt * 4 + w) * 4) * 64 + l) * 8;
  bf16x8 qf0 = *(const bf16x8*)(qb);
  bf16x8 qf1 = *(const bf16x8*)(qb + 512);
  bf16x8 qf2 = *(const bf16x8*)(qb + 1024);
  bf16x8 qf3 = *(const bf16x8*)(qb + 1536);

  const ushort* kbase = kpk + (size_t)bh * 131072 + l * 8;  // 64 tiles * 2048
  const ushort* vbase = vpk + (size_t)bh * 131072 + l * 8;

  f32x16 oacc0, oacc1;
#pragma unroll
  for (int r = 0; r < 16; ++r) { oacc0[r] = 0.f; oacc1[r] = 0.f; }
  float m = -1e30f, lsum = 0.f;
  const f32x16 z16 = {};

#define LOADK(k0, k1, k2, k3, kt) {                                           \
    const ushort* p_ = kbase + (size_t)(kt) * 2048;                           \
    k0 = *(const bf16x8*)(p_);        k1 = *(const bf16x8*)(p_ + 512);        \
    k2 = *(const bf16x8*)(p_ + 1024); k3 = *(const bf16x8*)(p_ + 1536); }
#define LOADV(v0, v1, v2, v3, kt) {                                           \
    const ushort* p_ = vbase + (size_t)(kt) * 2048;                           \
    v0 = *(const bf16x8*)(p_);        v1 = *(const bf16x8*)(p_ + 512);        \
    v2 = *(const bf16x8*)(p_ + 1024); v3 = *(const bf16x8*)(p_ + 1536); }

#define STEP(k0, k1, k2, k3, v0, v1, v2, v3) {                                \
    f32x16 s = __builtin_amdgcn_mfma_f32_32x32x16_bf16(k0, qf0, z16, 0, 0, 0);\
    s = __builtin_amdgcn_mfma_f32_32x32x16_bf16(k1, qf1, s, 0, 0, 0);         \
    s = __builtin_amdgcn_mfma_f32_32x32x16_bf16(k2, qf2, s, 0, 0, 0);         \
    s = __builtin_amdgcn_mfma_f32_32x32x16_bf16(k3, qf3, s, 0, 0, 0);         \
    float tm = s[0];                                                          \
    _Pragma("unroll") for (int r = 1; r < 16; ++r) tm = fmaxf(tm, s[r]);      \
    tm = fmaxf(tm, __shfl_xor(tm, 32));                                       \
    if (!__all(tm - m <= 8.f)) {                                              \
      const float mn = fmaxf(m, tm);                                          \
      const float sf = EXP2(m - mn);                                          \
      m = mn;                                                                 \
      lsum *= sf;                                                             \
      _Pragma("unroll") for (int r = 0; r < 16; ++r) {                        \
        const float f = __shfl(sf, (r & 3) + 8 * (r >> 2) + 4 * hi);          \
        oacc0[r] *= f; oacc1[r] *= f;                                         \
      }                                                                       \
    }                                                                         \
    float p[16];                                                              \
    _Pragma("unroll") for (int r = 0; r < 16; ++r) p[r] = EXP2(s[r] - m);     \
    float ls = 0.f;                                                           \
    _Pragma("unroll") for (int r = 0; r < 16; ++r) ls += p[r];                \
    lsum += ls;                                                               \
    unsigned pw[8];                                                           \
    _Pragma("unroll") for (int i = 0; i < 8; ++i)                             \
      asm("v_cvt_pk_bf16_f32 %0, %1, %2" : "=v"(pw[i]) : "v"(p[2*i]), "v"(p[2*i+1])); \
    unsigned a0 = pw[0], b0 = pw[2];                                          \
    asm("v_permlane32_swap_b32 %0, %1" : "+v"(a0), "+v"(b0));                 \
    unsigned a1 = pw[1], b1 = pw[3];                                          \
    asm("v_permlane32_swap_b32 %0, %1" : "+v"(a1), "+v"(b1));                 \
    unsigned a2 = pw[4], b2 = pw[6];                                          \
    asm("v_permlane32_swap_b32 %0, %1" : "+v"(a2), "+v"(b2));                 \
    unsigned a3 = pw[5], b3 = pw[7];                                          \
    asm("v_permlane32_swap_b32 %0, %1" : "+v"(a3), "+v"(b3));                 \
    union { unsigned uw[4]; bf16x8 v; } pa0, pa1;                             \
    pa0.uw[0] = a0; pa0.uw[1] = a1; pa0.uw[2] = b0; pa0.uw[3] = b1;           \
    pa1.uw[0] = a2; pa1.uw[1] = a3; pa1.uw[2] = b2; pa1.uw[3] = b3;           \
    oacc0 = __builtin_amdgcn_mfma_f32_32x32x16_bf16(pa0.v, v0, oacc0, 0, 0, 0);\
    oacc1 = __builtin_amdgcn_mfma_f32_32x32x16_bf16(pa0.v, v1, oacc1, 0, 0, 0);\
    oacc0 = __builtin_amdgcn_mfma_f32_32x32x16_bf16(pa1.v, v2, oacc0, 0, 0, 0);\
    oacc1 = __builtin_amdgcn_mfma_f32_32x32x16_bf16(pa1.v, v3, oacc1, 0, 0, 0);}

  bf16x8 ka0, ka1, ka2, ka3, kc0, kc1, kc2, kc3;
  LOADK(ka0, ka1, ka2, ka3, 0);
  for (int kt = 0; kt < 64; kt += 2) {
    bf16x8 va0, va1, va2, va3;
    LOADV(va0, va1, va2, va3, kt);
    LOADK(kc0, kc1, kc2, kc3, kt + 1);
    STEP(ka0, ka1, ka2, ka3, va0, va1, va2, va3);
    LOADV(va0, va1, va2, va3, kt + 1);
    if (kt + 2 < 64) LOADK(ka0, ka1, ka2, ka3, kt + 2);
    STEP(kc0, kc1, kc2, kc3, va0, va1, va2, va3);
  }
#undef LOADK
#undef LOADV
#undef STEP

  // --- normalize + store ctx[b*S+q][h*64 + d] ---
  const float lf = lsum + __shfl_xor(lsum, 32);
  const float linv = 1.f / lf;
#pragma unroll
  for (int r = 0; r < 16; ++r) {
    const int qr = (r & 3) + 8 * (r >> 2);
    const float fac = __shfl(linv, qr + 4 * hi);
    const int row = qt * 128 + w * 32 + qr + 4 * hi;
    const size_t base = ((size_t)(b * SEQ + row)) * HID + h * 64 + l32;
    ctx[base]      = f2bf(oacc0[r] * fac);
    ctx[base + 32] = f2bf(oacc1[r] * fac);
  }
}

// ---------------------------------------------------------------------------
extern "C" void kernel_launch(void* const* d_in, const int* in_sizes, int n_in,
                              void* d_out, int out_size, void* d_ws, size_t ws_size,
                              hipStream_t stream) {
  const float* x      = (const float*)d_in[0];
  const float* ln1g   = (const float*)d_in[1];
  const float* ln1b   = (const float*)d_in[2];
  const float* w_qkv  = (const float*)d_in[3];
  const float* b_qkv  = (const float*)d_in[4];
  const float* w_proj = (const float*)d_in[5];
  const float* b_proj = (const float*)d_in[6];
  const float* ln2g   = (const float*)d_in[7];
  const float* ln2b   = (const float*)d_in[8];
  const float* w1     = (const float*)d_in[9];
  const float* b1     = (const float*)d_in[10];
  const float* w2     = (const float*)d_in[11];
  const float* b2     = (const float*)d_in[12];

  char* ws = (char*)d_ws;
  ushort* wqkvT  = (ushort*)(ws + 0);             // [6144][2048] bf16  24MB
  ushort* wprojT = (ushort*)(ws + 25165824);      // [2048][2048] bf16   8MB
  ushort* w1T    = (ushort*)(ws + 33554432);      // [8192][2048] bf16  32MB
  ushort* w2T    = (ushort*)(ws + 67108864);      // [2048][8192] bf16  32MB
  ushort* hbuf   = (ushort*)(ws + 100663296);     // [4096][2048] bf16  16MB (LN1/LN2 out)
  ushort* qpk    = (ushort*)(ws + 117440512);     // packed Q 16MB
  ushort* kpk    = (ushort*)(ws + 134217728);     // packed K 16MB
  ushort* vpk    = (ushort*)(ws + 150994944);     // packed V 16MB
  ushort* ctxb   = (ushort*)(ws + 167772160);     // [4096][2048] bf16  16MB
  ushort* gelu   = (ushort*)(ws + 117440512);     // [4096][8192] bf16  64MB (reuses q/k/v/ctx)
  float*  x2     = (float*)(ws + 184549376);      // [4096][2048] f32   32MB  (ends 216MB)

  tcvt_kernel<<<dim3(96, 32),  256, 0, stream>>>(w_qkv,  wqkvT, 2048, 6144);
  tcvt_kernel<<<dim3(32, 32),  256, 0, stream>>>(w_proj, wprojT, 2048, 2048);
  tcvt_kernel<<<dim3(128, 32), 256, 0, stream>>>(w1,     w1T,   2048, 8192);
  tcvt_kernel<<<dim3(32, 128), 256, 0, stream>>>(w2,     w2T,   8192, 2048);

  // LN1 -> hbuf (bf16)
  ln_kernel<<<NTOK, 256, 0, stream>>>(x, ln1g, ln1b, hbuf);
  // QKV = h @ w_qkv + b_qkv, written fragment-packed (Q pre-scaled)
  gemm_qkv_kernel<<<dim3(48, 32), 256, 0, stream>>>(hbuf, wqkvT, b_qkv, qpk, kpk, vpk, NTOK, QKVW, HID);
  // attention -> ctxb (bf16)
  attn_kernel<<<dim3(16, 2 * NHEAD), 256, 0, stream>>>(qpk, kpk, vpk, ctxb);
  // x2 = ctx @ w_proj + b_proj + x   (f32)
  gemm_kernel<1><<<dim3(16, 32), 256, 0, stream>>>(ctxb, wprojT, b_proj, x, x2, NTOK, HID, HID);
  // LN2 -> hbuf
  ln_kernel<<<NTOK, 256, 0, stream>>>(x2, ln2g, ln2b, hbuf);
  // g = gelu(h @ w1 + b1)  (overwrites q/k/v/ctx region — all dead)
  gemm_kernel<2><<<dim3(64, 32), 256, 0, stream>>>(hbuf, w1T, b1, nullptr, gelu, NTOK, NFFN, HID);
  // out = g @ w2 + b2 + x2
  gemm_kernel<1><<<dim3(16, 32), 256, 0, stream>>>(gelu, w2T, b2, x2, (float*)d_out, NTOK, HID, NFFN);
}

// Round 4
// 748.352 us; speedup vs baseline: 1.3816x; 1.1337x over previous
//
#include <hip/hip_runtime.h>
#include <hip/hip_bf16.h>
#include <math.h>

// ---------------------------------------------------------------------------
// BasicTransformer block on MI355X, bf16-MFMA implementation.
// B=2 S=2048 H=2048 NH=32 HD=64 FFN=8192
// R4: all GEMMs on the 8-phase 256-wide template (T1 XCD swizzle, T2 LDS
// XOR-swizzle, T3/T4 phase pipeline w/ loads-in-flight, T5 setprio).
// Attention: zero-LDS fragment-packed (from R3).
// ---------------------------------------------------------------------------

typedef __attribute__((ext_vector_type(8))) short bf16x8;
typedef __attribute__((ext_vector_type(4))) float f32x4;
typedef __attribute__((ext_vector_type(16))) float f32x16;

#define DEV __device__ __forceinline__

static constexpr int SEQ  = 2048;
static constexpr int HID  = 2048;
static constexpr int NHEAD = 32;
static constexpr int HDIM = 64;
static constexpr int NFFN = 8192;
static constexpr int NTOK = 2 * SEQ;       // 4096 rows
static constexpr int QKVW = 3 * HID;       // 6144

// 0.125 (1/sqrt(64)) * log2(e): folded into Q so P = exp2(S - m)
#define QSCALE 0.1803368801111204f

#if defined(__has_builtin)
#if __has_builtin(__builtin_amdgcn_exp2f)
#define EXP2(x) __builtin_amdgcn_exp2f(x)
#endif
#endif
#ifndef EXP2
#define EXP2(x) exp2f(x)
#endif

DEV ushort f2bf(float f) {                 // RNE f32 -> bf16
  unsigned u = __float_as_uint(f);
  return (ushort)((u + 0x7fffu + ((u >> 16) & 1u)) >> 16);
}

DEV void gload16(const void* g, void* l) { // async global->LDS, 16B/lane
  __builtin_amdgcn_global_load_lds(
      (const __attribute__((address_space(1))) unsigned int*)g,
      (__attribute__((address_space(3))) unsigned int*)l, 16, 0, 0);
}

// ---------------------------------------------------------------------------
// transpose + convert: in [R][C] f32  ->  out [C][R] bf16
// ---------------------------------------------------------------------------
__global__ __launch_bounds__(256) void tcvt_kernel(const float* __restrict__ in,
                                                   ushort* __restrict__ out,
                                                   int R, int C) {
  __shared__ ushort tile[64][72];
  const int tr = blockIdx.y * 64, tc = blockIdx.x * 64;
  const int t = threadIdx.x;
  const int rr = t >> 2, c4 = (t & 3) * 16;
  const float4* ip = (const float4*)(in + (size_t)(tr + rr) * C + tc + c4);
  float4 a0 = ip[0], a1 = ip[1], a2 = ip[2], a3 = ip[3];
  ushort* tp = &tile[rr][c4];
  tp[0]=f2bf(a0.x); tp[1]=f2bf(a0.y); tp[2]=f2bf(a0.z); tp[3]=f2bf(a0.w);
  tp[4]=f2bf(a1.x); tp[5]=f2bf(a1.y); tp[6]=f2bf(a1.z); tp[7]=f2bf(a1.w);
  tp[8]=f2bf(a2.x); tp[9]=f2bf(a2.y); tp[10]=f2bf(a2.z); tp[11]=f2bf(a2.w);
  tp[12]=f2bf(a3.x); tp[13]=f2bf(a3.y); tp[14]=f2bf(a3.z); tp[15]=f2bf(a3.w);
  __syncthreads();
  union { ushort u[8]; bf16x8 v; } p0, p1;
#pragma unroll
  for (int j = 0; j < 8; ++j) { p0.u[j] = tile[c4 + j][rr]; p1.u[j] = tile[c4 + 8 + j][rr]; }
  ushort* op = out + (size_t)(tc + rr) * R + tr + c4;
  *(bf16x8*)op = p0.v;
  *(bf16x8*)(op + 8) = p1.v;
}

// ---------------------------------------------------------------------------
// LayerNorm row kernel: x [rows][2048] f32 -> out bf16
// ---------------------------------------------------------------------------
__global__ __launch_bounds__(256) void ln_kernel(const float* __restrict__ x,
                                                 const float* __restrict__ g,
                                                 const float* __restrict__ bb,
                                                 ushort* __restrict__ out) {
  const int row = blockIdx.x, t = threadIdx.x;
  const float4* xv = (const float4*)(x + (size_t)row * HID);
  float4 a0 = xv[t * 2], a1 = xv[t * 2 + 1];
  float s  = a0.x + a0.y + a0.z + a0.w + a1.x + a1.y + a1.z + a1.w;
  float ss = a0.x*a0.x + a0.y*a0.y + a0.z*a0.z + a0.w*a0.w
           + a1.x*a1.x + a1.y*a1.y + a1.z*a1.z + a1.w*a1.w;
#pragma unroll
  for (int o = 32; o > 0; o >>= 1) { s += __shfl_down(s, o); ss += __shfl_down(ss, o); }
  __shared__ float red[8];
  const int w = t >> 6, l = t & 63;
  if (l == 0) { red[w] = s; red[4 + w] = ss; }
  __syncthreads();
  s  = red[0] + red[1] + red[2] + red[3];
  ss = red[4] + red[5] + red[6] + red[7];
  const float mu = s * (1.f / HID);
  const float rs = rsqrtf(ss * (1.f / HID) - mu * mu + 1e-5f);
  const float4* gv = (const float4*)g;
  const float4* bv = (const float4*)bb;
  float4 g0 = gv[t * 2], g1 = gv[t * 2 + 1], b0 = bv[t * 2], b1 = bv[t * 2 + 1];
  union { ushort u[8]; bf16x8 v; } p;
  p.u[0] = f2bf((a0.x - mu) * rs * g0.x + b0.x);
  p.u[1] = f2bf((a0.y - mu) * rs * g0.y + b0.y);
  p.u[2] = f2bf((a0.z - mu) * rs * g0.z + b0.z);
  p.u[3] = f2bf((a0.w - mu) * rs * g0.w + b0.w);
  p.u[4] = f2bf((a1.x - mu) * rs * g1.x + b1.x);
  p.u[5] = f2bf((a1.y - mu) * rs * g1.y + b1.y);
  p.u[6] = f2bf((a1.z - mu) * rs * g1.z + b1.z);
  p.u[7] = f2bf((a1.w - mu) * rs * g1.w + b1.w);
  *(bf16x8*)(out + (size_t)row * HID + t * 8) = p.v;
}

// ---------------------------------------------------------------------------
// QKV fragment-packed store (same layout the attn kernel consumes).
// ---------------------------------------------------------------------------
DEV void qkv_store(int row, int col, float v,
                   ushort* __restrict__ qpk, ushort* __restrict__ kpk,
                   ushort* __restrict__ vpk) {
  const int h = col / 192;
  const int c = col - h * 192;
  const int bh2 = (row >> 11) * 32 + h;
  const int t32 = (row >> 5) & 63;
  const int r5 = row & 31;
  if (c < 64) {
    const int s = c >> 4, hi2 = (c >> 3) & 1, j = c & 7;
    qpk[(((size_t)bh2 * 64 + t32) * 4 + s) * 512 + (hi2 * 32 + r5) * 8 + j] = f2bf(v * QSCALE);
  } else if (c < 128) {
    const int d = c - 64;
    const int s = d >> 4, hi2 = (d >> 3) & 1, j = d & 7;
    kpk[(((size_t)bh2 * 64 + t32) * 4 + s) * 512 + (hi2 * 32 + r5) * 8 + j] = f2bf(v);
  } else {
    const int d = c - 128;
    const int ks = r5 >> 4, hi2 = (r5 >> 3) & 1, j = r5 & 7;
    const int half = d >> 5, dl = d & 31;
    vpk[((((size_t)bh2 * 64 + t32) * 2 + ks) * 2 + half) * 512 + (hi2 * 32 + dl) * 8 + j] = f2bf(v);
  }
}

// ---------------------------------------------------------------------------
// 8-phase GEMM. C[M,N] = A[M,K] * BT[N,K]^T, bf16 in, fp32 acc.
// BN=256, BK=64, 512 thr (8 waves 2Mx4N). LDS XOR-swizzled (slot ^= row&7),
// staged linear-dest + inverse-swizzled global source (rule #21).
// EPI 1: +bias+res->f32   2: +bias,gelu->bf16   3: QKV fragment-pack
// ---------------------------------------------------------------------------
DEV bf16x8 ldsfrag(const char* base, int row, int slot) {
  return *(const bf16x8*)(base + row * 128 + (((slot ^ (row & 7)) << 4)));
}

DEV void stage_one(const ushort* __restrict__ src, int Kd, int trow, int kt,
                   char* dst, int w, int lr, int lsl, int i) {
  const int g = i * 8 + w;                       // 8-row group index
  gload16(src + (size_t)(trow + g * 8 + lr) * Kd + kt + ((lsl ^ lr) << 3),
          dst + (g * 8 + lr) * 128 + lsl * 16);  // linear dest = base + tid*16
}

template <int BM, int EPI>
__global__ __launch_bounds__(512, 2) void gemm8p_kernel(
    const ushort* __restrict__ A, const ushort* __restrict__ BT,
    const float* __restrict__ bias, const float* __restrict__ res,
    void* __restrict__ outv,
    ushort* __restrict__ qpk, ushort* __restrict__ kpk, ushort* __restrict__ vpk,
    int M, int N, int K) {
  constexpr int MR = BM / 32;          // M fragments per wave (8 or 4)
  constexpr int MH = MR / 2;           // M fragments per quadrant
  constexpr int AI = BM / 64;          // A stage instrs per wave (4 or 2)
  constexpr int NI = AI + 4;           // total stage instrs per wave
  constexpr int SPP = (BM == 256) ? 3 : 2;  // stages issued per phase (ph 0..2)

  __shared__ ushort lds[2 * (BM * 64 + 256 * 64)];
  char* const a0p = (char*)lds;
  char* const b0p = a0p + BM * 128;
  char* const a1p = b0p + 32768;
  char* const b1p = a1p + BM * 128;

  const int t = threadIdx.x;
  const int w = t >> 6, l = t & 63;
  const int l16 = l & 15, lg = l >> 4;
  const int lr = l >> 3, lsl = l & 7;          // staging row-in-group / slot
  const int wm = w >> 2, wn = w & 3;

  // T1: XCD-bijective swizzle (all grids are multiples of 8 blocks)
  const int nwg = gridDim.x * gridDim.y;
  const int lin = blockIdx.y * gridDim.x + blockIdx.x;
  const int work = (lin & 7) * (nwg >> 3) + (lin >> 3);
  const int bn = work % gridDim.x, bm = work / gridDim.x;
  const int tm = bm * BM, tn = bn * 256;

  const f32x4 z4 = {0.f, 0.f, 0.f, 0.f};
  f32x4 acc[MR][4];
#pragma unroll
  for (int i = 0; i < MR; ++i)
#pragma unroll
    for (int j = 0; j < 4; ++j) acc[i][j] = z4;

  // prologue: stage K-tile 0 into buf0, drain, barrier
#pragma unroll
  for (int j = 0; j < NI; ++j) {
    if (j < 4) stage_one(BT, K, tn, 0, b0p, w, lr, lsl, j);
    else       stage_one(A,  K, tm, 0, a0p, w, lr, lsl, j - 4);
  }
  asm volatile("s_waitcnt vmcnt(0)" ::: "memory");
  __builtin_amdgcn_s_barrier();

#define KTILE(CA, CB, NA, NB, KTN, DOST)                                       \
  {                                                                            \
    _Pragma("unroll")                                                          \
    for (int q = 0; q < 4; ++q) {                                              \
      const int mh = q >> 1, nh = q & 1;                                       \
      bf16x8 af[MH][2], bfr[2][2];                                             \
      _Pragma("unroll")                                                        \
      for (int mi = 0; mi < MH; ++mi)                                          \
        _Pragma("unroll")                                                      \
        for (int ks = 0; ks < 2; ++ks)                                         \
          af[mi][ks] = ldsfrag(CA, wm * (BM / 2) + mh * (MH * 16) + mi * 16 + l16, ks * 4 + lg); \
      _Pragma("unroll")                                                        \
      for (int ni = 0; ni < 2; ++ni)                                           \
        _Pragma("unroll")                                                      \
        for (int ks = 0; ks < 2; ++ks)                                         \
          bfr[ni][ks] = ldsfrag(CB, wn * 64 + nh * 32 + ni * 16 + l16, ks * 4 + lg); \
      if (DOST) {                                                              \
        _Pragma("unroll")                                                      \
        for (int j = 0; j < SPP; ++j) {                                        \
          const int jj = q * SPP + j;                                          \
          if (jj < NI) {                                                       \
            if (jj < 4) stage_one(BT, K, tn, (KTN), NB, w, lr, lsl, jj);       \
            else        stage_one(A,  K, tm, (KTN), NA, w, lr, lsl, jj - 4);   \
          }                                                                    \
        }                                                                      \
      }                                                                        \
      __builtin_amdgcn_s_barrier();                                            \
      asm volatile("s_waitcnt lgkmcnt(0)" ::: "memory");                       \
      __builtin_amdgcn_sched_barrier(0);                                       \
      __builtin_amdgcn_s_setprio(1);                                           \
      _Pragma("unroll")                                                        \
      for (int mi = 0; mi < MH; ++mi)                                          \
        _Pragma("unroll")                                                      \
        for (int ni = 0; ni < 2; ++ni)                                         \
          _Pragma("unroll")                                                    \
          for (int ks = 0; ks < 2; ++ks)                                       \
            acc[mh * MH + mi][nh * 2 + ni] = __builtin_amdgcn_mfma_f32_16x16x32_bf16( \
                af[mi][ks], bfr[ni][ks], acc[mh * MH + mi][nh * 2 + ni], 0, 0, 0); \
      __builtin_amdgcn_s_setprio(0);                                           \
      if (q == 3 && (DOST)) asm volatile("s_waitcnt vmcnt(0)" ::: "memory");   \
      __builtin_amdgcn_s_barrier();                                            \
    }                                                                          \
  }

  const int nt = K >> 6;                 // K-tiles (even: 32 or 128)
  for (int it = 0; it < nt; it += 2) {
    KTILE(a0p, b0p, a1p, b1p, (it + 1) << 6, true);
    KTILE(a1p, b1p, a0p, b0p, (it + 2) << 6, (it + 2) < nt);
  }
#undef KTILE

  // epilogue
  const int row0 = tm + wm * (BM / 2) + lg * 4;
  const int col0 = tn + wn * 64 + l16;
#pragma unroll
  for (int ni = 0; ni < 4; ++ni) {
    const int col = col0 + ni * 16;
    const float bvl = bias[col];
#pragma unroll
    for (int mi = 0; mi < MR; ++mi) {
#pragma unroll
      for (int r = 0; r < 4; ++r) {
        const int row = row0 + mi * 16 + r;
        float v = acc[mi][ni][r] + bvl;
        if (EPI == 1) {
          const size_t off = (size_t)row * N + col;
          ((float*)outv)[off] = v + res[off];
        } else if (EPI == 2) {
          const float u = 0.7978845608f * (v + 0.044715f * v * v * v);
          ((ushort*)outv)[(size_t)row * N + col] = f2bf(v / (1.f + __expf(-2.f * u)));
        } else if (EPI == 3) {
          qkv_store(row, col, v, qpk, kpk, vpk);
        } else {
          ((ushort*)outv)[(size_t)row * N + col] = f2bf(v);
        }
      }
    }
  }
}

// ---------------------------------------------------------------------------
// Flash attention v3: zero-LDS, all operands fragment-packed & coalesced.
// Grid (16,64). 4 indep waves/block, wave = 32 q rows, KV tile = 32.
// ---------------------------------------------------------------------------
__global__ __launch_bounds__(256) void attn_kernel(const ushort* __restrict__ qpk,
                                                   const ushort* __restrict__ kpk,
                                                   const ushort* __restrict__ vpk,
                                                   ushort* __restrict__ ctx) {
  const int lin = blockIdx.x + blockIdx.y * gridDim.x;
  const int work = (lin & 7) * 128 + (lin >> 3);
  const int qt = work & 15, bh = work >> 4;
  const int b = bh >> 5, h = bh & 31;
  const int t = threadIdx.x, w = t >> 6, l = t & 63;
  const int l32 = l & 31, hi = l >> 5;

  const ushort* qb = qpk + ((((size_t)bh * 64 + qt * 4 + w) * 4) * 64 + l) * 8;
  bf16x8 qf0 = *(const bf16x8*)(qb);
  bf16x8 qf1 = *(const bf16x8*)(qb + 512);
  bf16x8 qf2 = *(const bf16x8*)(qb + 1024);
  bf16x8 qf3 = *(const bf16x8*)(qb + 1536);

  const ushort* kbase = kpk + (size_t)bh * 131072 + l * 8;
  const ushort* vbase = vpk + (size_t)bh * 131072 + l * 8;

  f32x16 oacc0, oacc1;
#pragma unroll
  for (int r = 0; r < 16; ++r) { oacc0[r] = 0.f; oacc1[r] = 0.f; }
  float m = -1e30f, lsum = 0.f;
  const f32x16 z16 = {};

#define LOADK(k0, k1, k2, k3, kt) {                                           \
    const ushort* p_ = kbase + (size_t)(kt) * 2048;                           \
    k0 = *(const bf16x8*)(p_);        k1 = *(const bf16x8*)(p_ + 512);        \
    k2 = *(const bf16x8*)(p_ + 1024); k3 = *(const bf16x8*)(p_ + 1536); }
#define LOADV(v0, v1, v2, v3, kt) {                                           \
    const ushort* p_ = vbase + (size_t)(kt) * 2048;                           \
    v0 = *(const bf16x8*)(p_);        v1 = *(const bf16x8*)(p_ + 512);        \
    v2 = *(const bf16x8*)(p_ + 1024); v3 = *(const bf16x8*)(p_ + 1536); }

#define STEP(k0, k1, k2, k3, v0, v1, v2, v3) {                                \
    f32x16 s = __builtin_amdgcn_mfma_f32_32x32x16_bf16(k0, qf0, z16, 0, 0, 0);\
    s = __builtin_amdgcn_mfma_f32_32x32x16_bf16(k1, qf1, s, 0, 0, 0);         \
    s = __builtin_amdgcn_mfma_f32_32x32x16_bf16(k2, qf2, s, 0, 0, 0);         \
    s = __builtin_amdgcn_mfma_f32_32x32x16_bf16(k3, qf3, s, 0, 0, 0);         \
    float tm = s[0];                                                          \
    _Pragma("unroll") for (int r = 1; r < 16; ++r) tm = fmaxf(tm, s[r]);      \
    tm = fmaxf(tm, __shfl_xor(tm, 32));                                       \
    if (!__all(tm - m <= 8.f)) {                                              \
      const float mn = fmaxf(m, tm);                                          \
      const float sf = EXP2(m - mn);                                          \
      m = mn;                                                                 \
      lsum *= sf;                                                             \
      _Pragma("unroll") for (int r = 0; r < 16; ++r) {                        \
        const float f = __shfl(sf, (r & 3) + 8 * (r >> 2) + 4 * hi);          \
        oacc0[r] *= f; oacc1[r] *= f;                                         \
      }                                                                       \
    }                                                                         \
    float p[16];                                                              \
    _Pragma("unroll") for (int r = 0; r < 16; ++r) p[r] = EXP2(s[r] - m);     \
    float ls = 0.f;                                                           \
    _Pragma("unroll") for (int r = 0; r < 16; ++r) ls += p[r];                \
    lsum += ls;                                                               \
    unsigned pw[8];                                                           \
    _Pragma("unroll") for (int i = 0; i < 8; ++i)                             \
      asm("v_cvt_pk_bf16_f32 %0, %1, %2" : "=v"(pw[i]) : "v"(p[2*i]), "v"(p[2*i+1])); \
    unsigned a0 = pw[0], b0 = pw[2];                                          \
    asm("v_permlane32_swap_b32 %0, %1" : "+v"(a0), "+v"(b0));                 \
    unsigned a1 = pw[1], b1 = pw[3];                                          \
    asm("v_permlane32_swap_b32 %0, %1" : "+v"(a1), "+v"(b1));                 \
    unsigned a2 = pw[4], b2 = pw[6];                                          \
    asm("v_permlane32_swap_b32 %0, %1" : "+v"(a2), "+v"(b2));                 \
    unsigned a3 = pw[5], b3 = pw[7];                                          \
    asm("v_permlane32_swap_b32 %0, %1" : "+v"(a3), "+v"(b3));                 \
    union { unsigned uw[4]; bf16x8 v; } pa0, pa1;                             \
    pa0.uw[0] = a0; pa0.uw[1] = a1; pa0.uw[2] = b0; pa0.uw[3] = b1;           \
    pa1.uw[0] = a2; pa1.uw[1] = a3; pa1.uw[2] = b2; pa1.uw[3] = b3;           \
    oacc0 = __builtin_amdgcn_mfma_f32_32x32x16_bf16(pa0.v, v0, oacc0, 0, 0, 0);\
    oacc1 = __builtin_amdgcn_mfma_f32_32x32x16_bf16(pa0.v, v1, oacc1, 0, 0, 0);\
    oacc0 = __builtin_amdgcn_mfma_f32_32x32x16_bf16(pa1.v, v2, oacc0, 0, 0, 0);\
    oacc1 = __builtin_amdgcn_mfma_f32_32x32x16_bf16(pa1.v, v3, oacc1, 0, 0, 0);}

  bf16x8 ka0, ka1, ka2, ka3, kc0, kc1, kc2, kc3;
  LOADK(ka0, ka1, ka2, ka3, 0);
  for (int kt = 0; kt < 64; kt += 2) {
    bf16x8 va0, va1, va2, va3;
    LOADV(va0, va1, va2, va3, kt);
    LOADK(kc0, kc1, kc2, kc3, kt + 1);
    STEP(ka0, ka1, ka2, ka3, va0, va1, va2, va3);
    LOADV(va0, va1, va2, va3, kt + 1);
    if (kt + 2 < 64) LOADK(ka0, ka1, ka2, ka3, kt + 2);
    STEP(kc0, kc1, kc2, kc3, va0, va1, va2, va3);
  }
#undef LOADK
#undef LOADV
#undef STEP

  const float lf = lsum + __shfl_xor(lsum, 32);
  const float linv = 1.f / lf;
#pragma unroll
  for (int r = 0; r < 16; ++r) {
    const int qr = (r & 3) + 8 * (r >> 2);
    const float fac = __shfl(linv, qr + 4 * hi);
    const int row = qt * 128 + w * 32 + qr + 4 * hi;
    const size_t base = ((size_t)(b * SEQ + row)) * HID + h * 64 + l32;
    ctx[base]      = f2bf(oacc0[r] * fac);
    ctx[base + 32] = f2bf(oacc1[r] * fac);
  }
}

// ---------------------------------------------------------------------------
extern "C" void kernel_launch(void* const* d_in, const int* in_sizes, int n_in,
                              void* d_out, int out_size, void* d_ws, size_t ws_size,
                              hipStream_t stream) {
  const float* x      = (const float*)d_in[0];
  const float* ln1g   = (const float*)d_in[1];
  const float* ln1b   = (const float*)d_in[2];
  const float* w_qkv  = (const float*)d_in[3];
  const float* b_qkv  = (const float*)d_in[4];
  const float* w_proj = (const float*)d_in[5];
  const float* b_proj = (const float*)d_in[6];
  const float* ln2g   = (const float*)d_in[7];
  const float* ln2b   = (const float*)d_in[8];
  const float* w1     = (const float*)d_in[9];
  const float* b1     = (const float*)d_in[10];
  const float* w2     = (const float*)d_in[11];
  const float* b2     = (const float*)d_in[12];

  char* ws = (char*)d_ws;
  ushort* wqkvT  = (ushort*)(ws + 0);             // [6144][2048] bf16  24MB
  ushort* wprojT = (ushort*)(ws + 25165824);      // [2048][2048] bf16   8MB
  ushort* w1T    = (ushort*)(ws + 33554432);      // [8192][2048] bf16  32MB
  ushort* w2T    = (ushort*)(ws + 67108864);      // [2048][8192] bf16  32MB
  ushort* hbuf   = (ushort*)(ws + 100663296);     // [4096][2048] bf16  16MB (LN1/LN2 out)
  ushort* qpk    = (ushort*)(ws + 117440512);     // packed Q 16MB
  ushort* kpk    = (ushort*)(ws + 134217728);     // packed K 16MB
  ushort* vpk    = (ushort*)(ws + 150994944);     // packed V 16MB
  ushort* ctxb   = (ushort*)(ws + 167772160);     // [4096][2048] bf16  16MB
  ushort* gelu   = (ushort*)(ws + 117440512);     // [4096][8192] bf16  64MB (reuses q/k/v/ctx)
  float*  x2     = (float*)(ws + 184549376);      // [4096][2048] f32   32MB

  tcvt_kernel<<<dim3(96, 32),  256, 0, stream>>>(w_qkv,  wqkvT, 2048, 6144);
  tcvt_kernel<<<dim3(32, 32),  256, 0, stream>>>(w_proj, wprojT, 2048, 2048);
  tcvt_kernel<<<dim3(128, 32), 256, 0, stream>>>(w1,     w1T,   2048, 8192);
  tcvt_kernel<<<dim3(32, 128), 256, 0, stream>>>(w2,     w2T,   8192, 2048);

  // LN1 -> hbuf (bf16)
  ln_kernel<<<NTOK, 256, 0, stream>>>(x, ln1g, ln1b, hbuf);
  // QKV = h @ w_qkv + b_qkv, fragment-packed out. grid 24x32 = 768 (3.0/CU)
  gemm8p_kernel<128, 3><<<dim3(24, 32), 512, 0, stream>>>(
      hbuf, wqkvT, b_qkv, nullptr, nullptr, qpk, kpk, vpk, NTOK, QKVW, HID);
  // attention -> ctxb (bf16)
  attn_kernel<<<dim3(16, 2 * NHEAD), 256, 0, stream>>>(qpk, kpk, vpk, ctxb);
  // x2 = ctx @ w_proj + b_proj + x (f32). grid 8x32 = 256 (1.0/CU)
  gemm8p_kernel<128, 1><<<dim3(8, 32), 512, 0, stream>>>(
      ctxb, wprojT, b_proj, x, x2, nullptr, nullptr, nullptr, NTOK, HID, HID);
  // LN2 -> hbuf
  ln_kernel<<<NTOK, 256, 0, stream>>>(x2, ln2g, ln2b, hbuf);
  // g = gelu(h @ w1 + b1). grid 32x16 = 512 (2.0/CU), BM=256
  gemm8p_kernel<256, 2><<<dim3(32, 16), 512, 0, stream>>>(
      hbuf, w1T, b1, nullptr, gelu, nullptr, nullptr, nullptr, NTOK, NFFN, HID);
  // out = g @ w2 + b2 + x2. grid 8x32 = 256 (1.0/CU)
  gemm8p_kernel<128, 1><<<dim3(8, 32), 512, 0, stream>>>(
      gelu, w2T, b2, x2, (float*)d_out, nullptr, nullptr, nullptr, NTOK, HID, NFFN);
}

// Round 6
// 633.894 us; speedup vs baseline: 1.6311x; 1.1806x over previous
//
#include <hip/hip_runtime.h>
#include <hip/hip_bf16.h>
#include <math.h>

// ---------------------------------------------------------------------------
// BasicTransformer block on MI355X, bf16-MFMA implementation.
// B=2 S=2048 H=2048 NH=32 HD=64 FFN=8192
// R5b: counted-vmcnt pipelining (T4): half-set staging in consume order,
// vmcnt(HALF) waits (never 0 mid-loop), 1 barrier/phase. (R5 + launch fix.)
// ---------------------------------------------------------------------------

typedef __attribute__((ext_vector_type(8))) short bf16x8;
typedef __attribute__((ext_vector_type(4))) float f32x4;
typedef __attribute__((ext_vector_type(16))) float f32x16;

#define DEV __device__ __forceinline__

static constexpr int SEQ  = 2048;
static constexpr int HID  = 2048;
static constexpr int NHEAD = 32;
static constexpr int HDIM = 64;
static constexpr int NFFN = 8192;
static constexpr int NTOK = 2 * SEQ;       // 4096 rows
static constexpr int QKVW = 3 * HID;       // 6144

// 0.125 (1/sqrt(64)) * log2(e): folded into Q so P = exp2(S - m)
#define QSCALE 0.1803368801111204f

#if defined(__has_builtin)
#if __has_builtin(__builtin_amdgcn_exp2f)
#define EXP2(x) __builtin_amdgcn_exp2f(x)
#endif
#endif
#ifndef EXP2
#define EXP2(x) exp2f(x)
#endif

#define VMCNT(n) asm volatile("s_waitcnt vmcnt(" #n ")" ::: "memory")

DEV ushort f2bf(float f) {                 // RNE f32 -> bf16
  unsigned u = __float_as_uint(f);
  return (ushort)((u + 0x7fffu + ((u >> 16) & 1u)) >> 16);
}

DEV void gload16(const void* g, void* l) { // async global->LDS, 16B/lane
  __builtin_amdgcn_global_load_lds(
      (const __attribute__((address_space(1))) unsigned int*)g,
      (__attribute__((address_space(3))) unsigned int*)l, 16, 0, 0);
}

// ---------------------------------------------------------------------------
// transpose + convert: in [R][C] f32  ->  out [C][R] bf16
// ---------------------------------------------------------------------------
__global__ __launch_bounds__(256) void tcvt_kernel(const float* __restrict__ in,
                                                   ushort* __restrict__ out,
                                                   int R, int C) {
  __shared__ ushort tile[64][72];
  const int tr = blockIdx.y * 64, tc = blockIdx.x * 64;
  const int t = threadIdx.x;
  const int rr = t >> 2, c4 = (t & 3) * 16;
  const float4* ip = (const float4*)(in + (size_t)(tr + rr) * C + tc + c4);
  float4 a0 = ip[0], a1 = ip[1], a2 = ip[2], a3 = ip[3];
  ushort* tp = &tile[rr][c4];
  tp[0]=f2bf(a0.x); tp[1]=f2bf(a0.y); tp[2]=f2bf(a0.z); tp[3]=f2bf(a0.w);
  tp[4]=f2bf(a1.x); tp[5]=f2bf(a1.y); tp[6]=f2bf(a1.z); tp[7]=f2bf(a1.w);
  tp[8]=f2bf(a2.x); tp[9]=f2bf(a2.y); tp[10]=f2bf(a2.z); tp[11]=f2bf(a2.w);
  tp[12]=f2bf(a3.x); tp[13]=f2bf(a3.y); tp[14]=f2bf(a3.z); tp[15]=f2bf(a3.w);
  __syncthreads();
  union { ushort u[8]; bf16x8 v; } p0, p1;
#pragma unroll
  for (int j = 0; j < 8; ++j) { p0.u[j] = tile[c4 + j][rr]; p1.u[j] = tile[c4 + 8 + j][rr]; }
  ushort* op = out + (size_t)(tc + rr) * R + tr + c4;
  *(bf16x8*)op = p0.v;
  *(bf16x8*)(op + 8) = p1.v;
}

// ---------------------------------------------------------------------------
// LayerNorm row kernel: x [rows][2048] f32 -> out bf16
// ---------------------------------------------------------------------------
__global__ __launch_bounds__(256) void ln_kernel(const float* __restrict__ x,
                                                 const float* __restrict__ g,
                                                 const float* __restrict__ bb,
                                                 ushort* __restrict__ out) {
  const int row = blockIdx.x, t = threadIdx.x;
  const float4* xv = (const float4*)(x + (size_t)row * HID);
  float4 a0 = xv[t * 2], a1 = xv[t * 2 + 1];
  float s  = a0.x + a0.y + a0.z + a0.w + a1.x + a1.y + a1.z + a1.w;
  float ss = a0.x*a0.x + a0.y*a0.y + a0.z*a0.z + a0.w*a0.w
           + a1.x*a1.x + a1.y*a1.y + a1.z*a1.z + a1.w*a1.w;
#pragma unroll
  for (int o = 32; o > 0; o >>= 1) { s += __shfl_down(s, o); ss += __shfl_down(ss, o); }
  __shared__ float red[8];
  const int w = t >> 6, l = t & 63;
  if (l == 0) { red[w] = s; red[4 + w] = ss; }
  __syncthreads();
  s  = red[0] + red[1] + red[2] + red[3];
  ss = red[4] + red[5] + red[6] + red[7];
  const float mu = s * (1.f / HID);
  const float rs = rsqrtf(ss * (1.f / HID) - mu * mu + 1e-5f);
  const float4* gv = (const float4*)g;
  const float4* bv = (const float4*)bb;
  float4 g0 = gv[t * 2], g1 = gv[t * 2 + 1], b0 = bv[t * 2], b1 = bv[t * 2 + 1];
  union { ushort u[8]; bf16x8 v; } p;
  p.u[0] = f2bf((a0.x - mu) * rs * g0.x + b0.x);
  p.u[1] = f2bf((a0.y - mu) * rs * g0.y + b0.y);
  p.u[2] = f2bf((a0.z - mu) * rs * g0.z + b0.z);
  p.u[3] = f2bf((a0.w - mu) * rs * g0.w + b0.w);
  p.u[4] = f2bf((a1.x - mu) * rs * g1.x + b1.x);
  p.u[5] = f2bf((a1.y - mu) * rs * g1.y + b1.y);
  p.u[6] = f2bf((a1.z - mu) * rs * g1.z + b1.z);
  p.u[7] = f2bf((a1.w - mu) * rs * g1.w + b1.w);
  *(bf16x8*)(out + (size_t)row * HID + t * 8) = p.v;
}

// ---------------------------------------------------------------------------
// QKV fragment-packed store (layout the attn kernel consumes).
// ---------------------------------------------------------------------------
DEV void qkv_store(int row, int col, float v,
                   ushort* __restrict__ qpk, ushort* __restrict__ kpk,
                   ushort* __restrict__ vpk) {
  const int h = col / 192;
  const int c = col - h * 192;
  const int bh2 = (row >> 11) * 32 + h;
  const int t32 = (row >> 5) & 63;
  const int r5 = row & 31;
  if (c < 64) {
    const int s = c >> 4, hi2 = (c >> 3) & 1, j = c & 7;
    qpk[(((size_t)bh2 * 64 + t32) * 4 + s) * 512 + (hi2 * 32 + r5) * 8 + j] = f2bf(v * QSCALE);
  } else if (c < 128) {
    const int d = c - 64;
    const int s = d >> 4, hi2 = (d >> 3) & 1, j = d & 7;
    kpk[(((size_t)bh2 * 64 + t32) * 4 + s) * 512 + (hi2 * 32 + r5) * 8 + j] = f2bf(v);
  } else {
    const int d = c - 128;
    const int ks = r5 >> 4, hi2 = (r5 >> 3) & 1, j = r5 & 7;
    const int half = d >> 5, dl = d & 31;
    vpk[((((size_t)bh2 * 64 + t32) * 2 + ks) * 2 + half) * 512 + (hi2 * 32 + dl) * 8 + j] = f2bf(v);
  }
}

// ---------------------------------------------------------------------------
// 8-phase GEMM with counted-vmcnt pipeline.
// C[M,N] = A[M,K] * BT[N,K]^T, bf16 in, fp32 acc. BN=256, BK=64, 512 thr.
// LDS XOR-swizzle (slot ^= row&7): linear gload_lds dest + inv-swizzled
// global source + swizzled ds_read (rule #21).
// Stage halves in consume order; vmcnt(HALF) at ph0/ph3 ends, never 0 mid-loop.
// EPI 1: +bias+res->f32   2: +bias,gelu->bf16   3: QKV fragment-pack
// ---------------------------------------------------------------------------
DEV bf16x8 ldsfrag(const char* base, int row, int slot) {
  return *(const bf16x8*)(base + row * 128 + (((slot ^ (row & 7)) << 4)));
}

// A-half mh, instr s (BM=256: s in {0,1}; BM=128: s=0 only). 64 rows/instr.
template <int BM>
DEV void stageA(const ushort* __restrict__ A, int Kd, int tm, int kt,
                char* abuf, int w, int lr, int lsl, int mh, int s) {
  int row;
  if (BM == 256) {
    row = s * 128 + mh * 64 + w * 8 + lr;
  } else {
    const int ri = w * 8 + lr;
    row = (ri >> 5) * 64 + mh * 32 + (ri & 31);
  }
  gload16(A + (size_t)(tm + row) * Kd + kt + ((lsl ^ lr) << 3),
          abuf + row * 128 + lsl * 16);
}

// B-half nh (BN=256), instr s in {0,1}. rows {q*64 + nh*32 + [0,32)}.
DEV void stageB(const ushort* __restrict__ BT, int Kd, int tn, int kt,
                char* bbuf, int w, int lr, int lsl, int nh, int s) {
  const int ri = s * 64 + w * 8 + lr;
  const int row = (ri >> 5) * 64 + nh * 32 + (ri & 31);
  gload16(BT + (size_t)(tn + row) * Kd + kt + ((lsl ^ lr) << 3),
          bbuf + row * 128 + lsl * 16);
}

template <int BM>
DEV void ktile(const ushort* __restrict__ A, const ushort* __restrict__ BT,
               int K, int tm, int tn,
               const char* CA, const char* CB, char* NA, char* NB,
               int ktn, bool dost, int w, int l, f32x4 (&acc)[BM / 32][4]) {
  constexpr int MH = BM / 64;
  const int l16 = l & 15, lg = l >> 4, lr = l >> 3, lsl = l & 7;
  const int wm = w >> 2, wn = w & 3;
  bf16x8 af[MH][2];
#pragma unroll
  for (int q = 0; q < 4; ++q) {
    const int mh = q >> 1, nh = q & 1;
    if ((q & 1) == 0) {
#pragma unroll
      for (int mi = 0; mi < MH; ++mi)
#pragma unroll
        for (int ks = 0; ks < 2; ++ks)
          af[mi][ks] = ldsfrag(CA, wm * (BM / 2) + mh * (BM / 4) + mi * 16 + l16, ks * 4 + lg);
    }
    bf16x8 bfr[2][2];
#pragma unroll
    for (int ni = 0; ni < 2; ++ni)
#pragma unroll
      for (int ks = 0; ks < 2; ++ks)
        bfr[ni][ks] = ldsfrag(CB, wn * 64 + nh * 32 + ni * 16 + l16, ks * 4 + lg);
    // stage half q of next tile (consume order: ph0 -> {Ah0,Bh0}, ph1 -> {Ah1,Bh1})
    if (dost && q < 2) {
      stageA<BM>(A, K, tm, ktn, NA, w, lr, lsl, q, 0);
      if (BM == 256) stageA<BM>(A, K, tm, ktn, NA, w, lr, lsl, q, 1);
      stageB(BT, K, tn, ktn, NB, w, lr, lsl, q, 0);
      stageB(BT, K, tn, ktn, NB, w, lr, lsl, q, 1);
    }
    // counted waits: validate data consumed after the NEXT barrier
    if (q == 0) {
      if (dost) { if (BM == 256) VMCNT(4); else VMCNT(3); }
      else VMCNT(0);
    }
    if (q == 3 && dost) { if (BM == 256) VMCNT(4); else VMCNT(3); }
    __builtin_amdgcn_s_barrier();
    asm volatile("s_waitcnt lgkmcnt(0)" ::: "memory");
    __builtin_amdgcn_sched_barrier(0);
    __builtin_amdgcn_s_setprio(1);
#pragma unroll
    for (int mi = 0; mi < MH; ++mi)
#pragma unroll
      for (int ni = 0; ni < 2; ++ni)
#pragma unroll
        for (int ks = 0; ks < 2; ++ks)
          acc[mh * MH + mi][nh * 2 + ni] = __builtin_amdgcn_mfma_f32_16x16x32_bf16(
              af[mi][ks], bfr[ni][ks], acc[mh * MH + mi][nh * 2 + ni], 0, 0, 0);
    __builtin_amdgcn_s_setprio(0);
  }
}

template <int BM, int EPI>
__global__ __launch_bounds__(512, 2) void gemm8p_kernel(
    const ushort* __restrict__ A, const ushort* __restrict__ BT,
    const float* __restrict__ bias, const float* __restrict__ res,
    void* __restrict__ outv,
    ushort* __restrict__ qpk, ushort* __restrict__ kpk, ushort* __restrict__ vpk,
    int M, int N, int K) {
  constexpr int MR = BM / 32;

  __shared__ ushort lds[2 * (BM * 64 + 256 * 64)];
  char* const a0p = (char*)lds;
  char* const b0p = a0p + BM * 128;
  char* const a1p = b0p + 32768;
  char* const b1p = a1p + BM * 128;

  const int t = threadIdx.x;
  const int w = t >> 6, l = t & 63;
  const int l16 = l & 15, lg = l >> 4;
  const int lr = l >> 3, lsl = l & 7;
  const int wm = w >> 2, wn = w & 3;

  // T1: XCD-bijective swizzle (all grids are multiples of 8 blocks)
  const int nwg = gridDim.x * gridDim.y;
  const int lin = blockIdx.y * gridDim.x + blockIdx.x;
  const int work = (lin & 7) * (nwg >> 3) + (lin >> 3);
  const int bn = work % gridDim.x, bm = work / gridDim.x;
  const int tm = bm * BM, tn = bn * 256;

  const f32x4 z4 = {0.f, 0.f, 0.f, 0.f};
  f32x4 acc[MR][4];
#pragma unroll
  for (int i = 0; i < MR; ++i)
#pragma unroll
    for (int j = 0; j < 4; ++j) acc[i][j] = z4;

  // prologue: stage K-tile 0 fully, drain, barrier
#pragma unroll
  for (int mh = 0; mh < 2; ++mh) {
    stageA<BM>(A, K, tm, 0, a0p, w, lr, lsl, mh, 0);
    if (BM == 256) stageA<BM>(A, K, tm, 0, a0p, w, lr, lsl, mh, 1);
    stageB(BT, K, tn, 0, b0p, w, lr, lsl, mh, 0);
    stageB(BT, K, tn, 0, b0p, w, lr, lsl, mh, 1);
  }
  VMCNT(0);
  __builtin_amdgcn_s_barrier();

  const int nt = K >> 6;                 // K-tiles (even: 32 or 128)
  for (int it = 0; it < nt; it += 2) {
    ktile<BM>(A, BT, K, tm, tn, a0p, b0p, a1p, b1p, (it + 1) << 6, true, w, l, acc);
    ktile<BM>(A, BT, K, tm, tn, a1p, b1p, a0p, b0p, (it + 2) << 6, (it + 2) < nt, w, l, acc);
  }

  // epilogue
  const int row0 = tm + wm * (BM / 2) + lg * 4;
  const int col0 = tn + wn * 64 + l16;
#pragma unroll
  for (int ni = 0; ni < 4; ++ni) {
    const int col = col0 + ni * 16;
    const float bvl = bias[col];
#pragma unroll
    for (int mi = 0; mi < MR; ++mi) {
#pragma unroll
      for (int r = 0; r < 4; ++r) {
        const int row = row0 + mi * 16 + r;
        float v = acc[mi][ni][r] + bvl;
        if (EPI == 1) {
          const size_t off = (size_t)row * N + col;
          ((float*)outv)[off] = v + res[off];
        } else if (EPI == 2) {
          const float u = 0.7978845608f * (v + 0.044715f * v * v * v);
          ((ushort*)outv)[(size_t)row * N + col] = f2bf(v / (1.f + __expf(-2.f * u)));
        } else if (EPI == 3) {
          qkv_store(row, col, v, qpk, kpk, vpk);
        } else {
          ((ushort*)outv)[(size_t)row * N + col] = f2bf(v);
        }
      }
    }
  }
}

// ---------------------------------------------------------------------------
// Flash attention: zero-LDS, all operands fragment-packed & coalesced.
// Grid (16,64). 4 indep waves/block, wave = 32 q rows, KV tile = 32.
// ---------------------------------------------------------------------------
__global__ __launch_bounds__(256) void attn_kernel(const ushort* __restrict__ qpk,
                                                   const ushort* __restrict__ kpk,
                                                   const ushort* __restrict__ vpk,
                                                   ushort* __restrict__ ctx) {
  const int lin = blockIdx.x + blockIdx.y * gridDim.x;
  const int work = (lin & 7) * 128 + (lin >> 3);
  const int qt = work & 15, bh = work >> 4;
  const int b = bh >> 5, h = bh & 31;
  const int t = threadIdx.x, w = t >> 6, l = t & 63;
  const int l32 = l & 31, hi = l >> 5;

  const ushort* qb = qpk + ((((size_t)bh * 64 + qt * 4 + w) * 4) * 64 + l) * 8;
  bf16x8 qf0 = *(const bf16x8*)(qb);
  bf16x8 qf1 = *(const bf16x8*)(qb + 512);
  bf16x8 qf2 = *(const bf16x8*)(qb + 1024);
  bf16x8 qf3 = *(const bf16x8*)(qb + 1536);

  const ushort* kbase = kpk + (size_t)bh * 131072 + l * 8;
  const ushort* vbase = vpk + (size_t)bh * 131072 + l * 8;

  f32x16 oacc0, oacc1;
#pragma unroll
  for (int r = 0; r < 16; ++r) { oacc0[r] = 0.f; oacc1[r] = 0.f; }
  float m = -1e30f, lsum = 0.f;
  const f32x16 z16 = {};

#define LOADK(k0, k1, k2, k3, kt) {                                           \
    const ushort* p_ = kbase + (size_t)(kt) * 2048;                           \
    k0 = *(const bf16x8*)(p_);        k1 = *(const bf16x8*)(p_ + 512);        \
    k2 = *(const bf16x8*)(p_ + 1024); k3 = *(const bf16x8*)(p_ + 1536); }
#define LOADV(v0, v1, v2, v3, kt) {                                           \
    const ushort* p_ = vbase + (size_t)(kt) * 2048;                           \
    v0 = *(const bf16x8*)(p_);        v1 = *(const bf16x8*)(p_ + 512);        \
    v2 = *(const bf16x8*)(p_ + 1024); v3 = *(const bf16x8*)(p_ + 1536); }

#define STEP(k0, k1, k2, k3, v0, v1, v2, v3) {                                \
    f32x16 s = __builtin_amdgcn_mfma_f32_32x32x16_bf16(k0, qf0, z16, 0, 0, 0);\
    s = __builtin_amdgcn_mfma_f32_32x32x16_bf16(k1, qf1, s, 0, 0, 0);         \
    s = __builtin_amdgcn_mfma_f32_32x32x16_bf16(k2, qf2, s, 0, 0, 0);         \
    s = __builtin_amdgcn_mfma_f32_32x32x16_bf16(k3, qf3, s, 0, 0, 0);         \
    float tm_ = s[0];                                                         \
    _Pragma("unroll") for (int r = 1; r < 16; ++r) tm_ = fmaxf(tm_, s[r]);    \
    tm_ = fmaxf(tm_, __shfl_xor(tm_, 32));                                    \
    if (!__all(tm_ - m <= 8.f)) {                                             \
      const float mn = fmaxf(m, tm_);                                         \
      const float sf = EXP2(m - mn);                                          \
      m = mn;                                                                 \
      lsum *= sf;                                                             \
      _Pragma("unroll") for (int r = 0; r < 16; ++r) {                        \
        const float f = __shfl(sf, (r & 3) + 8 * (r >> 2) + 4 * hi);          \
        oacc0[r] *= f; oacc1[r] *= f;                                         \
      }                                                                       \
    }                                                                         \
    float p[16];                                                              \
    _Pragma("unroll") for (int r = 0; r < 16; ++r) p[r] = EXP2(s[r] - m);     \
    float ls = 0.f;                                                           \
    _Pragma("unroll") for (int r = 0; r < 16; ++r) ls += p[r];                \
    lsum += ls;                                                               \
    unsigned pw[8];                                                           \
    _Pragma("unroll") for (int i = 0; i < 8; ++i)                             \
      asm("v_cvt_pk_bf16_f32 %0, %1, %2" : "=v"(pw[i]) : "v"(p[2*i]), "v"(p[2*i+1])); \
    unsigned a0 = pw[0], b0 = pw[2];                                          \
    asm("v_permlane32_swap_b32 %0, %1" : "+v"(a0), "+v"(b0));                 \
    unsigned a1 = pw[1], b1 = pw[3];                                          \
    asm("v_permlane32_swap_b32 %0, %1" : "+v"(a1), "+v"(b1));                 \
    unsigned a2 = pw[4], b2 = pw[6];                                          \
    asm("v_permlane32_swap_b32 %0, %1" : "+v"(a2), "+v"(b2));                 \
    unsigned a3 = pw[5], b3 = pw[7];                                          \
    asm("v_permlane32_swap_b32 %0, %1" : "+v"(a3), "+v"(b3));                 \
    union { unsigned uw[4]; bf16x8 v; } pa0, pa1;                             \
    pa0.uw[0] = a0; pa0.uw[1] = a1; pa0.uw[2] = b0; pa0.uw[3] = b1;           \
    pa1.uw[0] = a2; pa1.uw[1] = a3; pa1.uw[2] = b2; pa1.uw[3] = b3;           \
    oacc0 = __builtin_amdgcn_mfma_f32_32x32x16_bf16(pa0.v, v0, oacc0, 0, 0, 0);\
    oacc1 = __builtin_amdgcn_mfma_f32_32x32x16_bf16(pa0.v, v1, oacc1, 0, 0, 0);\
    oacc0 = __builtin_amdgcn_mfma_f32_32x32x16_bf16(pa1.v, v2, oacc0, 0, 0, 0);\
    oacc1 = __builtin_amdgcn_mfma_f32_32x32x16_bf16(pa1.v, v3, oacc1, 0, 0, 0);}

  bf16x8 ka0, ka1, ka2, ka3, kc0, kc1, kc2, kc3;
  LOADK(ka0, ka1, ka2, ka3, 0);
  for (int kt = 0; kt < 64; kt += 2) {
    bf16x8 va0, va1, va2, va3;
    LOADV(va0, va1, va2, va3, kt);
    LOADK(kc0, kc1, kc2, kc3, kt + 1);
    STEP(ka0, ka1, ka2, ka3, va0, va1, va2, va3);
    LOADV(va0, va1, va2, va3, kt + 1);
    if (kt + 2 < 64) LOADK(ka0, ka1, ka2, ka3, kt + 2);
    STEP(kc0, kc1, kc2, kc3, va0, va1, va2, va3);
  }
#undef LOADK
#undef LOADV
#undef STEP

  const float lf = lsum + __shfl_xor(lsum, 32);
  const float linv = 1.f / lf;
#pragma unroll
  for (int r = 0; r < 16; ++r) {
    const int qr = (r & 3) + 8 * (r >> 2);
    const float fac = __shfl(linv, qr + 4 * hi);
    const int row = qt * 128 + w * 32 + qr + 4 * hi;
    const size_t base = ((size_t)(b * SEQ + row)) * HID + h * 64 + l32;
    ctx[base]      = f2bf(oacc0[r] * fac);
    ctx[base + 32] = f2bf(oacc1[r] * fac);
  }
}

// ---------------------------------------------------------------------------
extern "C" void kernel_launch(void* const* d_in, const int* in_sizes, int n_in,
                              void* d_out, int out_size, void* d_ws, size_t ws_size,
                              hipStream_t stream) {
  const float* x      = (const float*)d_in[0];
  const float* ln1g   = (const float*)d_in[1];
  const float* ln1b   = (const float*)d_in[2];
  const float* w_qkv  = (const float*)d_in[3];
  const float* b_qkv  = (const float*)d_in[4];
  const float* w_proj = (const float*)d_in[5];
  const float* b_proj = (const float*)d_in[6];
  const float* ln2g   = (const float*)d_in[7];
  const float* ln2b   = (const float*)d_in[8];
  const float* w1     = (const float*)d_in[9];
  const float* b1     = (const float*)d_in[10];
  const float* w2     = (const float*)d_in[11];
  const float* b2     = (const float*)d_in[12];

  char* ws = (char*)d_ws;
  ushort* wqkvT  = (ushort*)(ws + 0);             // [6144][2048] bf16  24MB
  ushort* wprojT = (ushort*)(ws + 25165824);      // [2048][2048] bf16   8MB
  ushort* w1T    = (ushort*)(ws + 33554432);      // [8192][2048] bf16  32MB
  ushort* w2T    = (ushort*)(ws + 67108864);      // [2048][8192] bf16  32MB
  ushort* hbuf   = (ushort*)(ws + 100663296);     // [4096][2048] bf16  16MB (LN1/LN2 out)
  ushort* qpk    = (ushort*)(ws + 117440512);     // packed Q 16MB
  ushort* kpk    = (ushort*)(ws + 134217728);     // packed K 16MB
  ushort* vpk    = (ushort*)(ws + 150994944);     // packed V 16MB
  ushort* ctxb   = (ushort*)(ws + 167772160);     // [4096][2048] bf16  16MB
  ushort* gelu   = (ushort*)(ws + 117440512);     // [4096][8192] bf16  64MB (reuses q/k/v/ctx)
  float*  x2     = (float*)(ws + 184549376);      // [4096][2048] f32   32MB

  tcvt_kernel<<<dim3(96, 32),  256, 0, stream>>>(w_qkv,  wqkvT, 2048, 6144);
  tcvt_kernel<<<dim3(32, 32),  256, 0, stream>>>(w_proj, wprojT, 2048, 2048);
  tcvt_kernel<<<dim3(128, 32), 256, 0, stream>>>(w1,     w1T,   2048, 8192);
  tcvt_kernel<<<dim3(32, 128), 256, 0, stream>>>(w2,     w2T,   8192, 2048);

  // LN1 -> hbuf (bf16)
  ln_kernel<<<NTOK, 256, 0, stream>>>(x, ln1g, ln1b, hbuf);
  // QKV = h @ w_qkv + b_qkv, fragment-packed out. grid 24x32 = 768
  gemm8p_kernel<128, 3><<<dim3(24, 32), 512, 0, stream>>>(
      hbuf, wqkvT, b_qkv, nullptr, nullptr, qpk, kpk, vpk, NTOK, QKVW, HID);
  // attention -> ctxb (bf16)
  attn_kernel<<<dim3(16, 2 * NHEAD), 256, 0, stream>>>(qpk, kpk, vpk, ctxb);
  // x2 = ctx @ w_proj + b_proj + x (f32). grid 8x32 = 256
  gemm8p_kernel<128, 1><<<dim3(8, 32), 512, 0, stream>>>(
      ctxb, wprojT, b_proj, x, x2, nullptr, nullptr, nullptr, NTOK, HID, HID);
  // LN2 -> hbuf
  ln_kernel<<<NTOK, 256, 0, stream>>>(x2, ln2g, ln2b, hbuf);
  // g = gelu(h @ w1 + b1). grid 32x16 = 512, BM=256
  gemm8p_kernel<256, 2><<<dim3(32, 16), 512, 0, stream>>>(
      hbuf, w1T, b1, nullptr, gelu, nullptr, nullptr, nullptr, NTOK, NFFN, HID);
  // out = g @ w2 + b2 + x2. grid 8x32 = 256
  gemm8p_kernel<128, 1><<<dim3(8, 32), 512, 0, stream>>>(
      gelu, w2T, b2, x2, (float*)d_out, nullptr, nullptr, nullptr, NTOK, HID, NFFN);
}